// Round 1
// 1038.018 us; speedup vs baseline: 1.4389x; 1.4389x over previous
//
#include <hip/hip_runtime.h>

// Problem constants
#define B_ 4
#define T_ 8192
#define C_ 1024
#define H_ 8
#define D_ 128
#define M_ (B_*T_)   // 32768 rows

typedef __attribute__((ext_vector_type(8))) short bf16x8;   // 8 bf16 = 4 VGPRs
typedef __attribute__((ext_vector_type(4))) float f32x4;

// ---------------------------------------------------------------- bf16 helpers
__device__ __forceinline__ unsigned short f2b(float f) {   // RNE f32->bf16
  union { float f; unsigned int u; } x; x.f = f;
  unsigned int r = x.u + 0x7fffu + ((x.u >> 16) & 1u);
  return (unsigned short)(r >> 16);
}
__device__ __forceinline__ float b2f(unsigned short u) {
  union { float f; unsigned int u; } x; x.u = ((unsigned int)u) << 16; return x.f;
}

// async global->LDS, 16B per lane. LDS dest is wave-uniform base + lane*16.
__device__ __forceinline__ void gl2lds16(const void* g, void* l) {
  __builtin_amdgcn_global_load_lds((const __attribute__((address_space(1))) void*)g,
                                   (__attribute__((address_space(3))) void*)l, 16, 0, 0);
}

// ---------------------------------------------------------------- wave utils
__device__ __forceinline__ float wave_sum(float v) {
#pragma unroll
  for (int off = 32; off > 0; off >>= 1) v += __shfl_xor(v, off, 64);
  return v;
}
__device__ __forceinline__ float wave_max(float v) {
#pragma unroll
  for (int off = 32; off > 0; off >>= 1) v = fmaxf(v, __shfl_xor(v, off, 64));
  return v;
}

// ---------------------------------------------------------------- MFMA GEMM + bias
// out[M,N] = A[M,K](bf16) @ Bt[N,K]^T(bf16) + bias[N]
// 128x128 tile, BK=64, 256 threads = 4 waves in 2x2, each wave 64x64 (4x4 MFMA tiles).
// LDS tiles 128 rows x 64 bf16 (128 B/row), 16B-chunk XOR swizzle: LDS(row,c)
// holds logical k-chunk c ^ (row&7)  -> conflict-free ds_read_b128 frag loads
// while keeping the linear lane-order layout global_load_lds requires.
// VTRANS=true (v projection): out is bf16 vT[32][128][8192]: vT[bh][e][t].
// Requires N==C_, gridDim.x==H_ (so blockIdx.x is the head index).
template<typename OutT, bool VTRANS=false>
__global__ __launch_bounds__(256) void mfma_gemm_bias(
    const unsigned short* __restrict__ A,   // [M][K] bf16
    const unsigned short* __restrict__ Bt,  // [N][K] bf16
    const float* __restrict__ bias,         // [N]
    OutT* __restrict__ out,                 // [M][N]  (or vT when VTRANS)
    int M, int N, int K)
{
  __shared__ __align__(16) char lds[32768];
  char* As = lds;
  char* Bs = lds + 16384;
  const int tid  = threadIdx.x;
  const int w    = tid >> 6, lane = tid & 63;
  const int bm   = blockIdx.y * 128, bn = blockIdx.x * 128;
  const int wrow = (w >> 1) * 64, wcol = (w & 1) * 64;
  const int l15  = lane & 15, l4 = lane >> 4;

  f32x4 acc[4][4] = {};

  // staging geometry: chunk ch = w*4+j (1 KB each); lane covers row ch*8+(lane>>3),
  // stored 16B-chunk c = lane&7; fetches logical k-chunk kc = c ^ (row&7).
  const int srow = lane >> 3;
  const int sc   = lane & 7;

  for (int k0 = 0; k0 < K; k0 += 64) {
    __syncthreads();   // previous iter's frag reads done before overwrite
#pragma unroll
    for (int j = 0; j < 4; ++j) {
      const int ch  = w * 4 + j;
      const int row = ch * 8 + srow;
      const int kc  = sc ^ (row & 7);
      const char* ga = (const char*)(A  + (size_t)(bm + row) * K + k0) + kc * 16;
      const char* gb = (const char*)(Bt + (size_t)(bn + row) * K + k0) + kc * 16;
      gl2lds16(ga, As + ch * 1024 + lane * 16);
      gl2lds16(gb, Bs + ch * 1024 + lane * 16);
    }
    __syncthreads();   // compiler drains vmcnt before s_barrier

#pragma unroll
    for (int ks = 0; ks < 2; ++ks) {
      bf16x8 af[4], bf[4];
#pragma unroll
      for (int i = 0; i < 4; ++i) {
        const int m  = wrow + i * 16 + l15;       // frag row (A) / row (B)
        const int n  = wcol + i * 16 + l15;
        const int kc = ks * 4 + l4;               // logical 16B k-chunk
        af[i] = *(const bf16x8*)(As + m * 128 + ((kc ^ (m & 7)) * 16));
        bf[i] = *(const bf16x8*)(Bs + n * 128 + ((kc ^ (n & 7)) * 16));
      }
#pragma unroll
      for (int i = 0; i < 4; ++i)
#pragma unroll
        for (int j = 0; j < 4; ++j)
          acc[i][j] = __builtin_amdgcn_mfma_f32_16x16x32_bf16(af[i], bf[j], acc[i][j], 0, 0, 0);
    }
  }

  // epilogue: C/D layout col = lane&15, row = (lane>>4)*4 + reg
#pragma unroll
  for (int j = 0; j < 4; ++j) {
    const int col = bn + wcol + j * 16 + l15;
    const float bv = bias[col];
    if constexpr (VTRANS) {
      const int e = wcol + j * 16 + l15;   // col within head
      const int h = bn >> 7;               // head index
#pragma unroll
      for (int i = 0; i < 4; ++i) {
        const int m = bm + wrow + i * 16 + l4 * 4;   // 4 consecutive global rows
        const int b = m >> 13, t = m & 8191;
        union { unsigned short u[4]; uint2 v; } pk;
#pragma unroll
        for (int r = 0; r < 4; ++r) pk.u[r] = f2b(acc[i][j][r] + bv);
        *(uint2*)((unsigned short*)out + ((size_t)(b * H_ + h) * D_ + e) * T_ + t) = pk.v;
      }
    } else {
#pragma unroll
      for (int i = 0; i < 4; ++i) {
        const int rbase = bm + wrow + i * 16 + l4 * 4;
#pragma unroll
        for (int r = 0; r < 4; ++r) {
          const float val = acc[i][j][r] + bv;
          if constexpr (sizeof(OutT) == 4)
            out[(size_t)(rbase + r) * N + col] = val;
          else
            ((unsigned short*)out)[(size_t)(rbase + r) * N + col] = f2b(val);
        }
      }
    }
  }
}

// ---------------------------------------------------------------- ctx via MFMA
// ctx[bh][d][e] += sum_{t in window} kT[bh][d][t] * vT[bh][e][t]
// 128x128 single output tile per (bh, kchunk); K window = 512 (8 x BK=64).
// grid (16 kchunks, 32 bh); fp32 atomicAdd reduce across kchunks.
__global__ __launch_bounds__(256) void ctx_mfma(
    const unsigned short* __restrict__ kT,   // [32][128][8192] bf16
    const unsigned short* __restrict__ vT,   // [32][128][8192] bf16
    float* __restrict__ ctx)                 // [32][128][128] fp32 (pre-zeroed)
{
  __shared__ __align__(16) char lds[32768];
  char* As = lds;
  char* Bs = lds + 16384;
  const int tid  = threadIdx.x;
  const int w    = tid >> 6, lane = tid & 63;
  const int bh   = blockIdx.y;
  const int kbase = blockIdx.x * 512;
  const int wrow = (w >> 1) * 64, wcol = (w & 1) * 64;
  const int l15  = lane & 15, l4 = lane >> 4;
  const unsigned short* A  = kT + (size_t)bh * (D_ * T_);
  const unsigned short* Bt = vT + (size_t)bh * (D_ * T_);

  f32x4 acc[4][4] = {};
  const int srow = lane >> 3;
  const int sc   = lane & 7;

  for (int k0 = kbase; k0 < kbase + 512; k0 += 64) {
    __syncthreads();
#pragma unroll
    for (int j = 0; j < 4; ++j) {
      const int ch  = w * 4 + j;
      const int row = ch * 8 + srow;
      const int kc  = sc ^ (row & 7);
      const char* ga = (const char*)(A  + (size_t)row * T_ + k0) + kc * 16;
      const char* gb = (const char*)(Bt + (size_t)row * T_ + k0) + kc * 16;
      gl2lds16(ga, As + ch * 1024 + lane * 16);
      gl2lds16(gb, Bs + ch * 1024 + lane * 16);
    }
    __syncthreads();

#pragma unroll
    for (int ks = 0; ks < 2; ++ks) {
      bf16x8 af[4], bf[4];
#pragma unroll
      for (int i = 0; i < 4; ++i) {
        const int m  = wrow + i * 16 + l15;
        const int n  = wcol + i * 16 + l15;
        const int kc = ks * 4 + l4;
        af[i] = *(const bf16x8*)(As + m * 128 + ((kc ^ (m & 7)) * 16));
        bf[i] = *(const bf16x8*)(Bs + n * 128 + ((kc ^ (n & 7)) * 16));
      }
#pragma unroll
      for (int i = 0; i < 4; ++i)
#pragma unroll
        for (int j = 0; j < 4; ++j)
          acc[i][j] = __builtin_amdgcn_mfma_f32_16x16x32_bf16(af[i], bf[j], acc[i][j], 0, 0, 0);
    }
  }

  float* cb = ctx + (size_t)bh * (D_ * D_);
#pragma unroll
  for (int j = 0; j < 4; ++j) {
    const int col = wcol + j * 16 + l15;
#pragma unroll
    for (int i = 0; i < 4; ++i) {
      const int rbase = wrow + i * 16 + l4 * 4;
#pragma unroll
      for (int r = 0; r < 4; ++r)
        atomicAdd(&cb[(size_t)(rbase + r) * D_ + col], acc[i][j][r]);
    }
  }
}

// ---------------------------------------------------------------- conversions
// fp32 -> bf16, n must be divisible by 2048 (grid sized exactly)
__global__ __launch_bounds__(256) void conv_bf16(
    const float* __restrict__ in, unsigned short* __restrict__ out)
{
  const size_t i = ((size_t)blockIdx.x * 256 + threadIdx.x) * 8;
  float4 a = *(const float4*)(in + i);
  float4 b = *(const float4*)(in + i + 4);
  union { unsigned short s[8]; uint4 v; } pk;
  pk.s[0] = f2b(a.x); pk.s[1] = f2b(a.y); pk.s[2] = f2b(a.z); pk.s[3] = f2b(a.w);
  pk.s[4] = f2b(b.x); pk.s[5] = f2b(b.y); pk.s[6] = f2b(b.z); pk.s[7] = f2b(b.w);
  *(uint4*)(out + i) = pk.v;
}

// W[K=1024][N=1024] fp32 -> Wt[N][K] bf16 (transpose + cast), 32x32 LDS tiles
__global__ __launch_bounds__(256) void convT_w(
    const float* __restrict__ W, unsigned short* __restrict__ Wt)
{
  __shared__ float s[32][33];
  const int k0 = blockIdx.x * 32, n0 = blockIdx.y * 32;
  const int tx = threadIdx.x & 31, ty = threadIdx.x >> 5;   // 32 x 8
#pragma unroll
  for (int r = ty; r < 32; r += 8) s[r][tx] = W[(size_t)(k0 + r) * 1024 + n0 + tx];
  __syncthreads();
#pragma unroll
  for (int r = ty; r < 32; r += 8) Wt[(size_t)(n0 + r) * 1024 + k0 + tx] = f2b(s[tx][r]);
}

// ---------------------------------------------------------------- k transpose
// k fp32 [M][C] (head h cols) -> kT bf16 [32][128][8192]   (kT[bh][d][t])
// 64 t x 64 d tile per block; grid (T/64=128, D/64=2, 32 bh).
// LDS pitch 65 ushorts => both scalar phases bank-conflict-free.
__global__ __launch_bounds__(256) void transpose_k(
    const float* __restrict__ k, unsigned short* __restrict__ kT)
{
  __shared__ unsigned short s[64][65];
  const int bh = blockIdx.z, b = bh >> 3, h = bh & 7;
  const int t0 = blockIdx.x * 64, d0 = blockIdx.y * 64;
  const int tid = threadIdx.x;

  const int rr = tid >> 4;          // 0..15 (t row)
  const int rc = tid & 15;          // d chunk (4 floats)
  const float* src = k + ((size_t)(b * T_ + t0 + rr)) * C_ + h * D_ + d0 + rc * 4;
#pragma unroll
  for (int i = 0; i < 4; ++i) {
    float4 v = *(const float4*)(src + (size_t)i * 16 * C_);
    const int t = rr + i * 16;
    s[rc * 4 + 0][t] = f2b(v.x);
    s[rc * 4 + 1][t] = f2b(v.y);
    s[rc * 4 + 2][t] = f2b(v.z);
    s[rc * 4 + 3][t] = f2b(v.w);
  }
  __syncthreads();

  const int wr = tid >> 3;          // 0..31 (d row)
  const int wc = tid & 7;           // t chunk (8 ushorts = 16B)
#pragma unroll
  for (int i = 0; i < 2; ++i) {
    const int d = wr + i * 32;
    union { unsigned short u[8]; uint4 v; } pk;
#pragma unroll
    for (int j = 0; j < 8; ++j) pk.u[j] = s[d][wc * 8 + j];
    *(uint4*)(kT + ((size_t)bh * D_ + d0 + d) * T_ + t0 + wc * 8) = pk.v;
  }
}

// ---------------------------------------------------------------- ksum from kT
// ksum[bh*128+d] = sum_t kT[bh][d][t]; one wave per row (4096 rows).
__global__ __launch_bounds__(256) void ksum_kernel(
    const unsigned short* __restrict__ kT, float* __restrict__ ksum)
{
  const int row  = blockIdx.x * 4 + (threadIdx.x >> 6);
  const int lane = threadIdx.x & 63;
  const unsigned short* p = kT + (size_t)row * T_ + lane * 8;
  float s = 0.f;
#pragma unroll
  for (int it = 0; it < 16; ++it) {
    union { uint4 v; unsigned short u[8]; } pk;
    pk.v = *(const uint4*)(p + (size_t)it * 512);
#pragma unroll
    for (int j = 0; j < 8; ++j) s += b2f(pk.u[j]);
  }
  s = wave_sum(s);
  if (lane == 0) ksum[row] = s;
}

// ---------------------------------------------------------------- softmax over D=128
// In-place softmax over each 128-wide head segment (fp32). One wave per (row, head).
// If ksum != nullptr (q pass): also dinv[bh*T + t] = 1/(q . ksum[bh]).
__global__ __launch_bounds__(256) void softmax_head(
    float* __restrict__ buf, const float* __restrict__ ksum, float* __restrict__ dinv)
{
  const int wave = threadIdx.x >> 6, lane = threadIdx.x & 63;
  const size_t rh  = (size_t)blockIdx.x * 4 + wave;   // rh = m*H + h
  const size_t off = rh * 128 + (size_t)lane * 2;
  float2 v = *(float2*)&buf[off];
  float mx = wave_max(fmaxf(v.x, v.y));
  float ex = expf(v.x - mx), ey = expf(v.y - mx);
  float inv = 1.0f / wave_sum(ex + ey);
  ex *= inv; ey *= inv;
  *(float2*)&buf[off] = make_float2(ex, ey);
  if (ksum) {
    const int m = (int)(rh >> 3), h = (int)(rh & 7);
    const int b = m >> 13, t = m & 8191;
    const int bh = b * 8 + h;
    const float* ks = ksum + (size_t)bh * 128 + lane * 2;
    float dot = wave_sum(ex * ks[0] + ey * ks[1]);
    if (lane == 0) dinv[(size_t)bh * T_ + t] = 1.0f / dot;
  }
}

// ---------------------------------------------------------------- y = (q @ ctx)*Dinv + q -> bf16
__global__ __launch_bounds__(256) void y_gemm(
    const float* __restrict__ q, const float* __restrict__ ctx,
    const float* __restrict__ dinv, unsigned short* __restrict__ yb)
{
  const int bh = blockIdx.y; const int b = bh >> 3, h = bh & 7;
  const int t0 = blockIdx.x * 128;
  const int tid  = threadIdx.x;
  const int arow = tid >> 2, acol = (tid & 3) << 2;
  const int brow = tid >> 5, bcol = (tid & 31) << 2;
  const int tx   = tid & 15, ty = tid >> 4;
  __shared__ float As[16][132];
  __shared__ float Bs[16][132];
  float acc[8][8] = {};
  const size_t qbase = ((size_t)b*T_ + t0) * C_ + (size_t)h * D_;
  const float* cbase = ctx + (size_t)bh * (D_*D_);

  for (int k0 = 0; k0 < 128; k0 += 16) {
    float4 a0 = *(const float4*)&q[qbase + (size_t)arow      * C_ + k0 + acol];
    float4 a1 = *(const float4*)&q[qbase + (size_t)(arow+64) * C_ + k0 + acol];
    float4 b0 = *(const float4*)&cbase[(size_t)(k0+brow  )*D_ + bcol];
    float4 b1 = *(const float4*)&cbase[(size_t)(k0+brow+8)*D_ + bcol];
    __syncthreads();
    As[acol+0][arow]    = a0.x; As[acol+1][arow]    = a0.y;
    As[acol+2][arow]    = a0.z; As[acol+3][arow]    = a0.w;
    As[acol+0][arow+64] = a1.x; As[acol+1][arow+64] = a1.y;
    As[acol+2][arow+64] = a1.z; As[acol+3][arow+64] = a1.w;
    *(float4*)&Bs[brow  ][bcol] = b0;
    *(float4*)&Bs[brow+8][bcol] = b1;
    __syncthreads();
#pragma unroll
    for (int kk = 0; kk < 16; ++kk) {
      float a[8], bb[8];
      *(float4*)&a[0]  = *(const float4*)&As[kk][ty*8];
      *(float4*)&a[4]  = *(const float4*)&As[kk][ty*8+4];
      *(float4*)&bb[0] = *(const float4*)&Bs[kk][tx*8];
      *(float4*)&bb[4] = *(const float4*)&Bs[kk][tx*8+4];
#pragma unroll
      for (int i = 0; i < 8; ++i)
#pragma unroll
        for (int j = 0; j < 8; ++j)
          acc[i][j] = fmaf(a[i], bb[j], acc[i][j]);
    }
  }

  const float* dv = dinv + (size_t)bh * T_ + t0;
#pragma unroll
  for (int i = 0; i < 8; ++i) {
    const int t = ty*8 + i;
    const float di = dv[t];
    const size_t ro = qbase + (size_t)t * C_ + tx*8;
    float4 q0 = *(const float4*)&q[ro];
    float4 q1 = *(const float4*)&q[ro+4];
    union { unsigned short s[8]; uint4 v; } pk;
    pk.s[0] = f2b(fmaf(acc[i][0], di, q0.x)); pk.s[1] = f2b(fmaf(acc[i][1], di, q0.y));
    pk.s[2] = f2b(fmaf(acc[i][2], di, q0.z)); pk.s[3] = f2b(fmaf(acc[i][3], di, q0.w));
    pk.s[4] = f2b(fmaf(acc[i][4], di, q1.x)); pk.s[5] = f2b(fmaf(acc[i][5], di, q1.y));
    pk.s[6] = f2b(fmaf(acc[i][6], di, q1.z)); pk.s[7] = f2b(fmaf(acc[i][7], di, q1.w));
    *(uint4*)&yb[ro] = pk.v;
  }
}

// ---------------------------------------------------------------- launch
extern "C" void kernel_launch(void* const* d_in, const int* in_sizes, int n_in,
                              void* d_out, int out_size, void* d_ws, size_t ws_size,
                              hipStream_t stream)
{
  const float* x  = (const float*)d_in[0];
  const float* Wq = (const float*)d_in[1];
  const float* bq = (const float*)d_in[2];
  const float* Wk = (const float*)d_in[3];
  const float* bk = (const float*)d_in[4];
  const float* Wv = (const float*)d_in[5];
  const float* bv = (const float*)d_in[6];
  const float* Wp = (const float*)d_in[7];
  const float* bp = (const float*)d_in[8];
  float* out = (float*)d_out;

  // workspace layout (bytes):
  //   xb  bf16 [M][C]      @   0   (64 MiB)   -- reused as kT after v-GEMM,
  //                                              then as yb after ctx_mfma
  //   q   fp32 [M][C]      @  64   (128 MiB)
  //   k   fp32 [M][C]      @ 192   (128 MiB)
  //   vT  bf16 [32][128][8192] @ 320 (64 MiB)
  //   Wt  bf16 4x[N][K]    @ 384   (8 MiB)
  //   ctx fp32 [32][128^2] @ 392   (2 MiB)
  //   ksum fp32            @ 394   (16 KiB)
  //   dinv fp32            @ 395   (1 MiB)     total ~396 MiB
  char* w = (char*)d_ws;
  unsigned short* xb = (unsigned short*)w;
  float* q  = (float*)(w + (64UL  << 20));
  float* k  = (float*)(w + (192UL << 20));
  unsigned short* vT = (unsigned short*)(w + (320UL << 20));
  unsigned short* Wtq = (unsigned short*)(w + (384UL << 20));
  unsigned short* Wtk = Wtq + 1024*1024;
  unsigned short* Wtv = Wtk + 1024*1024;
  unsigned short* Wtp = Wtv + 1024*1024;
  float* ctx  = (float*)(w + (392UL << 20));
  float* ksum = (float*)(w + (394UL << 20));
  float* dinv = (float*)(w + (395UL << 20));
  unsigned short* kT = xb;   // xb dead after v-GEMM; kT dead before y_gemm writes
  unsigned short* yb = xb;

  hipMemsetAsync(ctx, 0, 2UL << 20, stream);   // ctx partial-sum target

  dim3 blk(256);
  dim3 gconvT(32, 32);
  dim3 ggemm(C_/128, M_/128);   // 8 x 256

  conv_bf16<<<dim3(M_*C_/2048), blk, 0, stream>>>(x, xb);
  convT_w<<<gconvT, blk, 0, stream>>>(Wq, Wtq);
  convT_w<<<gconvT, blk, 0, stream>>>(Wk, Wtk);
  convT_w<<<gconvT, blk, 0, stream>>>(Wv, Wtv);
  convT_w<<<gconvT, blk, 0, stream>>>(Wp, Wtp);

  mfma_gemm_bias<float>              <<<ggemm, blk, 0, stream>>>(xb, Wtq, bq, q,  M_, C_, C_);
  mfma_gemm_bias<float>              <<<ggemm, blk, 0, stream>>>(xb, Wtk, bk, k,  M_, C_, C_);
  mfma_gemm_bias<unsigned short,true><<<ggemm, blk, 0, stream>>>(xb, Wtv, bv, (unsigned short*)vT, M_, C_, C_);

  softmax_head<<<dim3(M_*H_/4), blk, 0, stream>>>(k, nullptr, nullptr);
  transpose_k <<<dim3(T_/64, 2, B_*H_), blk, 0, stream>>>(k, kT);
  ksum_kernel <<<dim3(B_*H_*D_/4), blk, 0, stream>>>(kT, ksum);
  softmax_head<<<dim3(M_*H_/4), blk, 0, stream>>>(q, ksum, dinv);
  ctx_mfma    <<<dim3(16, B_*H_), blk, 0, stream>>>(kT, vT, ctx);
  y_gemm      <<<dim3(T_/128, B_*H_), blk, 0, stream>>>(q, ctx, dinv, yb);

  mfma_gemm_bias<float><<<ggemm, blk, 0, stream>>>(yb, Wtp, bp, out, M_, C_, C_);
}

// Round 2
// 853.777 us; speedup vs baseline: 1.7494x; 1.2158x over previous
//
#include <hip/hip_runtime.h>

// Problem constants
#define B_ 4
#define T_ 8192
#define C_ 1024
#define H_ 8
#define D_ 128
#define M_ (B_*T_)   // 32768 rows

typedef __attribute__((ext_vector_type(8))) short bf16x8;   // 8 bf16 = 4 VGPRs
typedef __attribute__((ext_vector_type(4))) float f32x4;

// ---------------------------------------------------------------- bf16 helpers
__device__ __forceinline__ unsigned short f2b(float f) {   // RNE f32->bf16
  union { float f; unsigned int u; } x; x.f = f;
  unsigned int r = x.u + 0x7fffu + ((x.u >> 16) & 1u);
  return (unsigned short)(r >> 16);
}
__device__ __forceinline__ float b2f(unsigned short u) {
  union { float f; unsigned int u; } x; x.u = ((unsigned int)u) << 16; return x.f;
}

// async global->LDS, 16B per lane. LDS dest is wave-uniform base + lane*16.
__device__ __forceinline__ void gl2lds16(const void* g, void* l) {
  __builtin_amdgcn_global_load_lds((const __attribute__((address_space(1))) void*)g,
                                   (__attribute__((address_space(3))) void*)l, 16, 0, 0);
}

// XCD-aware bijective swizzle for (8, 256) grids (nwg=2048, 8 XCDs, chunk=256).
// HW round-robins linearized blockIdx across XCDs; remap so each XCD gets a
// contiguous 4096-row band x all 8 col-tiles -> A-panel reuse in its L2.
__device__ __forceinline__ int swz_id() {
  const int orig = blockIdx.y * 8 + blockIdx.x;
  return (orig & 7) * 256 + (orig >> 3);
}

// ---------------------------------------------------------------- MFMA GEMM + bias
// out[M,N] = A[M,K](bf16) @ Bt[N,K]^T(bf16) + bias[N]
// 128x128 tile, BK=64, 256 threads = 4 waves in 2x2, each wave 64x64 (4x4 MFMA tiles).
// 16B-chunk XOR swizzle in LDS: LDS(row,c) holds logical k-chunk c ^ (row&7).
// VTRANS=true (v projection): out is bf16 vT[32][128][8192]: vT[bh][e][t].
// NOTE: grid must be (8, 256) (swz_id assumption).
template<typename OutT, bool VTRANS=false>
__global__ __launch_bounds__(256) void mfma_gemm_bias(
    const unsigned short* __restrict__ A,   // [M][K] bf16
    const unsigned short* __restrict__ Bt,  // [N][K] bf16
    const float* __restrict__ bias,         // [N]
    OutT* __restrict__ out,                 // [M][N]  (or vT when VTRANS)
    int M, int N, int K)
{
  __shared__ __align__(16) char lds[32768];
  char* As = lds;
  char* Bs = lds + 16384;
  const int tid  = threadIdx.x;
  const int w    = tid >> 6, lane = tid & 63;
  const int id   = swz_id();
  const int bm   = (id >> 3) * 128, bn = (id & 7) * 128;
  const int wrow = (w >> 1) * 64, wcol = (w & 1) * 64;
  const int l15  = lane & 15, l4 = lane >> 4;

  f32x4 acc[4][4] = {};

  const int srow = lane >> 3;
  const int sc   = lane & 7;

  for (int k0 = 0; k0 < K; k0 += 64) {
    __syncthreads();   // previous iter's frag reads done before overwrite
#pragma unroll
    for (int j = 0; j < 4; ++j) {
      const int ch  = w * 4 + j;
      const int row = ch * 8 + srow;
      const int kc  = sc ^ (row & 7);
      const char* ga = (const char*)(A  + (size_t)(bm + row) * K + k0) + kc * 16;
      const char* gb = (const char*)(Bt + (size_t)(bn + row) * K + k0) + kc * 16;
      gl2lds16(ga, As + ch * 1024 + lane * 16);
      gl2lds16(gb, Bs + ch * 1024 + lane * 16);
    }
    __syncthreads();   // compiler drains vmcnt before s_barrier

#pragma unroll
    for (int ks = 0; ks < 2; ++ks) {
      bf16x8 af[4], bf[4];
#pragma unroll
      for (int i = 0; i < 4; ++i) {
        const int m  = wrow + i * 16 + l15;
        const int n  = wcol + i * 16 + l15;
        const int kc = ks * 4 + l4;
        af[i] = *(const bf16x8*)(As + m * 128 + ((kc ^ (m & 7)) * 16));
        bf[i] = *(const bf16x8*)(Bs + n * 128 + ((kc ^ (n & 7)) * 16));
      }
#pragma unroll
      for (int i = 0; i < 4; ++i)
#pragma unroll
        for (int j = 0; j < 4; ++j)
          acc[i][j] = __builtin_amdgcn_mfma_f32_16x16x32_bf16(af[i], bf[j], acc[i][j], 0, 0, 0);
    }
  }

  // epilogue: C/D layout col = lane&15, row = (lane>>4)*4 + reg
#pragma unroll
  for (int j = 0; j < 4; ++j) {
    const int col = bn + wcol + j * 16 + l15;
    const float bv = bias[col];
    if constexpr (VTRANS) {
      const int e = wcol + j * 16 + l15;   // col within head
      const int h = bn >> 7;               // head index
#pragma unroll
      for (int i = 0; i < 4; ++i) {
        const int m = bm + wrow + i * 16 + l4 * 4;   // 4 consecutive global rows
        const int b = m >> 13, t = m & 8191;
        union { unsigned short u[4]; uint2 v; } pk;
#pragma unroll
        for (int r = 0; r < 4; ++r) pk.u[r] = f2b(acc[i][j][r] + bv);
        *(uint2*)((unsigned short*)out + ((size_t)(b * H_ + h) * D_ + e) * T_ + t) = pk.v;
      }
    } else {
#pragma unroll
      for (int i = 0; i < 4; ++i) {
        const int rbase = bm + wrow + i * 16 + l4 * 4;
#pragma unroll
        for (int r = 0; r < 4; ++r) {
          const float val = acc[i][j][r] + bv;
          if constexpr (sizeof(OutT) == 4)
            out[(size_t)(rbase + r) * N + col] = val;
          else
            ((unsigned short*)out)[(size_t)(rbase + r) * N + col] = f2b(val);
        }
      }
    }
  }
}

// ---------------------------------------------------------------- fused q/k projection
// GEMM (M x 1024 x 1024) + bias + softmax over the 128-col head segment.
// 4 waves in 4x1: each wave owns 32 full rows x 128 cols -> acc[2][8]; the
// softmax row-reduce is 8 in-register values + shfl_xor over the 16-lane group.
// KMODE:  write kT bf16 [32][128][8192] (transposed) + atomic ksum[bh][d]
//         (ksum accumulated from the bf16-ROUNDED values so dinv's denominator
//          matches what ctx_mfma consumes).
// !KMODE: round q to bf16, write qb [M][1024], compute dinv[bh][t]=1/(q.ksum).
// grid must be (8, 256).
template<bool KMODE>
__global__ __launch_bounds__(256) void qk_gemm_softmax(
    const unsigned short* __restrict__ A,    // [M][1024] bf16 (x)
    const unsigned short* __restrict__ Bt,   // [1024][1024] bf16 (W^T)
    const float* __restrict__ bias,          // [1024]
    unsigned short* __restrict__ kT,         // KMODE out
    unsigned short* __restrict__ qb,         // !KMODE out
    float* __restrict__ ksum,                // KMODE atomic accum [32][128] (pre-zeroed)
    const float* __restrict__ ksum_in,       // !KMODE in
    float* __restrict__ dinv)                // !KMODE out [32][8192]
{
  __shared__ __align__(16) char lds[32768];
  char* As = lds;
  char* Bs = lds + 16384;
  const int tid  = threadIdx.x;
  const int w    = tid >> 6, lane = tid & 63;
  const int id   = swz_id();
  const int bm   = (id >> 3) * 128, bn = (id & 7) * 128;
  const int wrow = w * 32;
  const int l15  = lane & 15, l4 = lane >> 4;

  f32x4 acc[2][8] = {};
  const int srow = lane >> 3;
  const int sc   = lane & 7;

  for (int k0 = 0; k0 < 1024; k0 += 64) {
    __syncthreads();
#pragma unroll
    for (int j = 0; j < 4; ++j) {
      const int ch  = w * 4 + j;
      const int row = ch * 8 + srow;
      const int kc  = sc ^ (row & 7);
      gl2lds16((const char*)(A  + (size_t)(bm + row) * 1024 + k0) + kc * 16, As + ch * 1024 + lane * 16);
      gl2lds16((const char*)(Bt + (size_t)(bn + row) * 1024 + k0) + kc * 16, Bs + ch * 1024 + lane * 16);
    }
    __syncthreads();

#pragma unroll
    for (int ks = 0; ks < 2; ++ks) {
      bf16x8 af[2], bf[8];
      const int kc = ks * 4 + l4;
#pragma unroll
      for (int i = 0; i < 2; ++i) {
        const int m = wrow + i * 16 + l15;
        af[i] = *(const bf16x8*)(As + m * 128 + ((kc ^ (m & 7)) * 16));
      }
#pragma unroll
      for (int j = 0; j < 8; ++j) {
        const int n = j * 16 + l15;
        bf[j] = *(const bf16x8*)(Bs + n * 128 + ((kc ^ (n & 7)) * 16));
      }
#pragma unroll
      for (int i = 0; i < 2; ++i)
#pragma unroll
        for (int j = 0; j < 8; ++j)
          acc[i][j] = __builtin_amdgcn_mfma_f32_16x16x32_bf16(af[i], bf[j], acc[i][j], 0, 0, 0);
    }
  }

  // ---- bias + softmax over 128 cols of each row (in-register) ----
  float bvj[8];
#pragma unroll
  for (int j = 0; j < 8; ++j) bvj[j] = bias[bn + j * 16 + l15];

#pragma unroll
  for (int i = 0; i < 2; ++i)
#pragma unroll
    for (int r = 0; r < 4; ++r) {
      float v[8];
      float mx = -1e30f;
#pragma unroll
      for (int j = 0; j < 8; ++j) { v[j] = acc[i][j][r] + bvj[j]; mx = fmaxf(mx, v[j]); }
#pragma unroll
      for (int off = 8; off > 0; off >>= 1) mx = fmaxf(mx, __shfl_xor(mx, off, 64));
      float s = 0.f;
#pragma unroll
      for (int j = 0; j < 8; ++j) { v[j] = expf(v[j] - mx); s += v[j]; }
#pragma unroll
      for (int off = 8; off > 0; off >>= 1) s += __shfl_xor(s, off, 64);
      const float inv = 1.0f / s;
#pragma unroll
      for (int j = 0; j < 8; ++j) acc[i][j][r] = v[j] * inv;
    }

  const int h  = bn >> 7;
  const int b  = bm >> 13;          // all 128 rows of this block share b
  const int bh = b * 8 + h;

  if constexpr (KMODE) {
    float csum[8];
#pragma unroll
    for (int j = 0; j < 8; ++j) csum[j] = 0.f;
#pragma unroll
    for (int j = 0; j < 8; ++j) {
      const int d = j * 16 + l15;
#pragma unroll
      for (int i = 0; i < 2; ++i) {
        const int t = (bm + wrow + i * 16 + l4 * 4) & 8191;
        union { unsigned short u[4]; uint2 v2; } pk;
#pragma unroll
        for (int r = 0; r < 4; ++r) {
          const unsigned short us = f2b(acc[i][j][r]);
          pk.u[r] = us;
          csum[j] += b2f(us);
        }
        *(uint2*)(kT + ((size_t)bh * 128 + d) * 8192 + t) = pk.v2;
      }
    }
    // column sums: reduce over l4 groups (lanes ^16,^32 share the same col)
#pragma unroll
    for (int j = 0; j < 8; ++j) {
      csum[j] += __shfl_xor(csum[j], 16, 64);
      csum[j] += __shfl_xor(csum[j], 32, 64);
    }
    __syncthreads();                 // all frag reads done -> LDS reusable
    float* red = (float*)lds;        // [4][128]
    if (l4 == 0) {
#pragma unroll
      for (int j = 0; j < 8; ++j) red[w * 128 + j * 16 + l15] = csum[j];
    }
    __syncthreads();
    if (tid < 128) {
      const float s2 = red[tid] + red[128 + tid] + red[256 + tid] + red[384 + tid];
      atomicAdd(&ksum[(size_t)bh * 128 + tid], s2);
    }
  } else {
    float ks8[8];
#pragma unroll
    for (int j = 0; j < 8; ++j) ks8[j] = ksum_in[(size_t)bh * 128 + j * 16 + l15];
#pragma unroll
    for (int i = 0; i < 2; ++i)
#pragma unroll
      for (int r = 0; r < 4; ++r) {
        const int m = bm + wrow + i * 16 + l4 * 4 + r;
        float dot = 0.f;
#pragma unroll
        for (int j = 0; j < 8; ++j) {
          acc[i][j][r] = b2f(f2b(acc[i][j][r]));   // use bf16-rounded q everywhere
          dot += acc[i][j][r] * ks8[j];
        }
#pragma unroll
        for (int off = 8; off > 0; off >>= 1) dot += __shfl_xor(dot, off, 64);
        if (l15 == 0) dinv[(size_t)bh * 8192 + (m & 8191)] = 1.0f / dot;
#pragma unroll
        for (int j = 0; j < 8; ++j)
          qb[(size_t)m * 1024 + bn + j * 16 + l15] = f2b(acc[i][j][r]);
      }
  }
}

// ---------------------------------------------------------------- ctx via MFMA
// ctxT[bh][e][d] += sum_{t in window} kT[bh][d][t] * vT[bh][e][t]   (TRANSPOSED store)
// grid (16 kchunks, 32 bh); fp32 atomicAdd reduce across kchunks.
__global__ __launch_bounds__(256) void ctx_mfma(
    const unsigned short* __restrict__ kT,   // [32][128][8192] bf16
    const unsigned short* __restrict__ vT,   // [32][128][8192] bf16
    float* __restrict__ ctxT)                // [32][128][128] fp32 (pre-zeroed), [e][d]
{
  __shared__ __align__(16) char lds[32768];
  char* As = lds;
  char* Bs = lds + 16384;
  const int tid  = threadIdx.x;
  const int w    = tid >> 6, lane = tid & 63;
  const int bh   = blockIdx.y;
  const int kbase = blockIdx.x * 512;
  const int wrow = (w >> 1) * 64, wcol = (w & 1) * 64;
  const int l15  = lane & 15, l4 = lane >> 4;
  const unsigned short* A  = kT + (size_t)bh * (D_ * T_);
  const unsigned short* Bt = vT + (size_t)bh * (D_ * T_);

  f32x4 acc[4][4] = {};
  const int srow = lane >> 3;
  const int sc   = lane & 7;

  for (int k0 = kbase; k0 < kbase + 512; k0 += 64) {
    __syncthreads();
#pragma unroll
    for (int j = 0; j < 4; ++j) {
      const int ch  = w * 4 + j;
      const int row = ch * 8 + srow;
      const int kc  = sc ^ (row & 7);
      gl2lds16((const char*)(A  + (size_t)row * T_ + k0) + kc * 16, As + ch * 1024 + lane * 16);
      gl2lds16((const char*)(Bt + (size_t)row * T_ + k0) + kc * 16, Bs + ch * 1024 + lane * 16);
    }
    __syncthreads();

#pragma unroll
    for (int ks = 0; ks < 2; ++ks) {
      bf16x8 af[4], bf[4];
#pragma unroll
      for (int i = 0; i < 4; ++i) {
        const int m  = wrow + i * 16 + l15;
        const int n  = wcol + i * 16 + l15;
        const int kc = ks * 4 + l4;
        af[i] = *(const bf16x8*)(As + m * 128 + ((kc ^ (m & 7)) * 16));
        bf[i] = *(const bf16x8*)(Bs + n * 128 + ((kc ^ (n & 7)) * 16));
      }
#pragma unroll
      for (int i = 0; i < 4; ++i)
#pragma unroll
        for (int j = 0; j < 4; ++j)
          acc[i][j] = __builtin_amdgcn_mfma_f32_16x16x32_bf16(af[i], bf[j], acc[i][j], 0, 0, 0);
    }
  }

  float* cb = ctxT + (size_t)bh * (D_ * D_);
#pragma unroll
  for (int j = 0; j < 4; ++j) {
    const int col = wcol + j * 16 + l15;          // e
#pragma unroll
    for (int i = 0; i < 4; ++i) {
      const int rbase = wrow + i * 16 + l4 * 4;   // d
#pragma unroll
      for (int r = 0; r < 4; ++r)
        atomicAdd(&cb[(size_t)col * D_ + rbase + r], acc[i][j][r]);   // ctxT[e][d]
    }
  }
}

// ---------------------------------------------------------------- y via MFMA
// y[t][e] = (sum_d qb[t][d]*ctxTb[e][d]) * dinv[t] + qb[t][e]  -> yb bf16
// Same 128x128 structure, K=128 (2 BK iters). grid must be (8, 256).
__global__ __launch_bounds__(256) void y_mfma(
    const unsigned short* __restrict__ qb,     // [M][1024] bf16 (softmaxed q)
    const unsigned short* __restrict__ ctxTb,  // [32][128][128] bf16  ctxT[e][d]
    const float* __restrict__ dinv,            // [32][8192]
    unsigned short* __restrict__ yb)           // [M][1024] bf16
{
  __shared__ __align__(16) char lds[32768];
  char* As = lds;
  char* Bs = lds + 16384;
  const int tid  = threadIdx.x;
  const int w    = tid >> 6, lane = tid & 63;
  const int id   = swz_id();
  const int bm   = (id >> 3) * 128, bn = (id & 7) * 128;
  const int wrow = (w >> 1) * 64, wcol = (w & 1) * 64;
  const int l15  = lane & 15, l4 = lane >> 4;
  const int h = bn >> 7, b = bm >> 13, bh = b * 8 + h;
  const unsigned short* Bt = ctxTb + (size_t)bh * (D_ * D_);

  f32x4 acc[4][4] = {};
  const int srow = lane >> 3;
  const int sc   = lane & 7;

#pragma unroll
  for (int k0 = 0; k0 < 128; k0 += 64) {
    __syncthreads();
#pragma unroll
    for (int j = 0; j < 4; ++j) {
      const int ch  = w * 4 + j;
      const int row = ch * 8 + srow;
      const int kc  = sc ^ (row & 7);
      gl2lds16((const char*)(qb + (size_t)(bm + row) * 1024 + bn + k0) + kc * 16, As + ch * 1024 + lane * 16);
      gl2lds16((const char*)(Bt + (size_t)row * 128 + k0) + kc * 16, Bs + ch * 1024 + lane * 16);
    }
    __syncthreads();

#pragma unroll
    for (int ks = 0; ks < 2; ++ks) {
      bf16x8 af[4], bf[4];
#pragma unroll
      for (int i = 0; i < 4; ++i) {
        const int m  = wrow + i * 16 + l15;
        const int n  = wcol + i * 16 + l15;
        const int kc = ks * 4 + l4;
        af[i] = *(const bf16x8*)(As + m * 128 + ((kc ^ (m & 7)) * 16));
        bf[i] = *(const bf16x8*)(Bs + n * 128 + ((kc ^ (n & 7)) * 16));
      }
#pragma unroll
      for (int i = 0; i < 4; ++i)
#pragma unroll
        for (int j = 0; j < 4; ++j)
          acc[i][j] = __builtin_amdgcn_mfma_f32_16x16x32_bf16(af[i], bf[j], acc[i][j], 0, 0, 0);
    }
  }

  float di[4][4];
#pragma unroll
  for (int i = 0; i < 4; ++i)
#pragma unroll
    for (int r = 0; r < 4; ++r)
      di[i][r] = dinv[(size_t)bh * 8192 + ((bm + wrow + i * 16 + l4 * 4 + r) & 8191)];

#pragma unroll
  for (int j = 0; j < 4; ++j) {
    const int col = bn + wcol + j * 16 + l15;
#pragma unroll
    for (int i = 0; i < 4; ++i) {
      const int m = bm + wrow + i * 16 + l4 * 4;
#pragma unroll
      for (int r = 0; r < 4; ++r) {
        const float qv = b2f(qb[(size_t)(m + r) * 1024 + col]);
        yb[(size_t)(m + r) * 1024 + col] = f2b(fmaf(acc[i][j][r], di[i][r], qv));
      }
    }
  }
}

// ---------------------------------------------------------------- conversions
// fp32 -> bf16, count must be divisible by 2048 (grid sized exactly)
__global__ __launch_bounds__(256) void conv_bf16(
    const float* __restrict__ in, unsigned short* __restrict__ out)
{
  const size_t i = ((size_t)blockIdx.x * 256 + threadIdx.x) * 8;
  float4 a = *(const float4*)(in + i);
  float4 b = *(const float4*)(in + i + 4);
  union { unsigned short s[8]; uint4 v; } pk;
  pk.s[0] = f2b(a.x); pk.s[1] = f2b(a.y); pk.s[2] = f2b(a.z); pk.s[3] = f2b(a.w);
  pk.s[4] = f2b(b.x); pk.s[5] = f2b(b.y); pk.s[6] = f2b(b.z); pk.s[7] = f2b(b.w);
  *(uint4*)(out + i) = pk.v;
}

// W[K=1024][N=1024] fp32 -> Wt[N][K] bf16 (transpose + cast), 32x32 LDS tiles
__global__ __launch_bounds__(256) void convT_w(
    const float* __restrict__ W, unsigned short* __restrict__ Wt)
{
  __shared__ float s[32][33];
  const int k0 = blockIdx.x * 32, n0 = blockIdx.y * 32;
  const int tx = threadIdx.x & 31, ty = threadIdx.x >> 5;   // 32 x 8
#pragma unroll
  for (int r = ty; r < 32; r += 8) s[r][tx] = W[(size_t)(k0 + r) * 1024 + n0 + tx];
  __syncthreads();
#pragma unroll
  for (int r = ty; r < 32; r += 8) Wt[(size_t)(n0 + r) * 1024 + k0 + tx] = f2b(s[tx][r]);
}

// ---------------------------------------------------------------- launch
extern "C" void kernel_launch(void* const* d_in, const int* in_sizes, int n_in,
                              void* d_out, int out_size, void* d_ws, size_t ws_size,
                              hipStream_t stream)
{
  const float* x  = (const float*)d_in[0];
  const float* Wq = (const float*)d_in[1];
  const float* bq = (const float*)d_in[2];
  const float* Wk = (const float*)d_in[3];
  const float* bk = (const float*)d_in[4];
  const float* Wv = (const float*)d_in[5];
  const float* bv = (const float*)d_in[6];
  const float* Wp = (const float*)d_in[7];
  const float* bp = (const float*)d_in[8];
  float* out = (float*)d_out;

  // workspace layout (MiB offsets):
  //   xb   bf16 [M][C]          @   0  (64)   -- reused as yb by y_mfma
  //   qb   bf16 [M][C]          @  64  (64)
  //   kT   bf16 [32][128][8192] @ 128  (64)
  //   vT   bf16 [32][128][8192] @ 192  (64)
  //   Wt   bf16 4x[N][K]        @ 256  (8)
  //   ctxT fp32 [32][128][128]  @ 264  (2)
  //   ksum fp32 [32][128]       @ 266  (16 KiB)
  //   dinv fp32 [32][8192]      @ 267  (1)
  //   ctxTb bf16                @ 268  (1)     total ~269 MiB
  char* w = (char*)d_ws;
  unsigned short* xb  = (unsigned short*)w;
  unsigned short* qb  = (unsigned short*)(w + (64UL  << 20));
  unsigned short* kT  = (unsigned short*)(w + (128UL << 20));
  unsigned short* vT  = (unsigned short*)(w + (192UL << 20));
  unsigned short* Wtq = (unsigned short*)(w + (256UL << 20));
  unsigned short* Wtk = Wtq + 1024*1024;
  unsigned short* Wtv = Wtk + 1024*1024;
  unsigned short* Wtp = Wtv + 1024*1024;
  float* ctxT  = (float*)(w + (264UL << 20));
  float* ksum  = (float*)(w + (266UL << 20));
  float* dinv  = (float*)(w + (267UL << 20));
  unsigned short* ctxTb = (unsigned short*)(w + (268UL << 20));
  unsigned short* yb = xb;   // xb dead after q projection

  hipMemsetAsync(ctxT, 0, (2UL << 20) + 16384, stream);   // ctxT + ksum (contiguous)

  dim3 blk(256);
  dim3 gconvT(32, 32);
  dim3 ggemm(C_/128, M_/128);   // (8, 256)

  conv_bf16<<<dim3(M_*C_/2048), blk, 0, stream>>>(x, xb);
  convT_w<<<gconvT, blk, 0, stream>>>(Wq, Wtq);
  convT_w<<<gconvT, blk, 0, stream>>>(Wk, Wtk);
  convT_w<<<gconvT, blk, 0, stream>>>(Wv, Wtv);
  convT_w<<<gconvT, blk, 0, stream>>>(Wp, Wtp);

  // k projection (fused softmax + transposed bf16 store + ksum)
  qk_gemm_softmax<true><<<ggemm, blk, 0, stream>>>(xb, Wtk, bk, kT, nullptr, ksum, nullptr, nullptr);
  // v projection (transposed bf16 store)
  mfma_gemm_bias<unsigned short, true><<<ggemm, blk, 0, stream>>>(xb, Wtv, bv, vT, M_, C_, C_);
  // q projection (fused softmax + dinv; needs completed ksum)
  qk_gemm_softmax<false><<<ggemm, blk, 0, stream>>>(xb, Wtq, bq, nullptr, qb, nullptr, ksum, dinv);

  ctx_mfma<<<dim3(16, B_*H_), blk, 0, stream>>>(kT, vT, ctxT);
  conv_bf16<<<dim3(32*128*128/2048), blk, 0, stream>>>(ctxT, ctxTb);
  y_mfma<<<ggemm, blk, 0, stream>>>(qb, ctxTb, dinv, yb);

  mfma_gemm_bias<float><<<ggemm, blk, 0, stream>>>(yb, Wtp, bp, out, M_, C_, C_);
}

// Round 3
// 767.385 us; speedup vs baseline: 1.9463x; 1.1126x over previous
//
#include <hip/hip_runtime.h>

// Problem constants
#define B_ 4
#define T_ 8192
#define C_ 1024
#define H_ 8
#define D_ 128
#define M_ (B_*T_)   // 32768 rows
#define NKC_ 32      // ctx k-chunks (t-windows of 256)

typedef __attribute__((ext_vector_type(8))) short bf16x8;   // 8 bf16 = 4 VGPRs
typedef __attribute__((ext_vector_type(4))) float f32x4;

// ---------------------------------------------------------------- bf16 helpers
__device__ __forceinline__ unsigned short f2b(float f) {   // RNE f32->bf16
  union { float f; unsigned int u; } x; x.f = f;
  unsigned int r = x.u + 0x7fffu + ((x.u >> 16) & 1u);
  return (unsigned short)(r >> 16);
}
__device__ __forceinline__ float b2f(unsigned short u) {
  union { float f; unsigned int u; } x; x.u = ((unsigned int)u) << 16; return x.f;
}

// async global->LDS, 16B per lane. LDS dest is wave-uniform base + lane*16.
__device__ __forceinline__ void gl2lds16(const void* g, void* l) {
  __builtin_amdgcn_global_load_lds((const __attribute__((address_space(1))) void*)g,
                                   (__attribute__((address_space(3))) void*)l, 16, 0, 0);
}

// XCD-aware bijective swizzle for (8, 256) grids (nwg=2048, 8 XCDs, chunk=256).
__device__ __forceinline__ int swz_id() {
  const int orig = blockIdx.y * 8 + blockIdx.x;
  return (orig & 7) * 256 + (orig >> 3);
}

// ---------------------------------------------------------------- MFMA GEMM + bias
// out[M,N] = A[M,K](bf16) @ Bt[N,K]^T(bf16) + bias[N]
// 128x128 tile, BK=64, 256 threads = 4 waves in 2x2, each wave 64x64 (4x4 MFMA tiles).
// 16B-chunk XOR swizzle in LDS: LDS(row,c) holds logical k-chunk c ^ (row&7).
// VTRANS=true (v projection): out is bf16 vT[32][128][8192]: vT[bh][e][t].
// NOTE: grid must be (8, 256) (swz_id assumption).
template<typename OutT, bool VTRANS=false>
__global__ __launch_bounds__(256) void mfma_gemm_bias(
    const unsigned short* __restrict__ A,   // [M][K] bf16
    const unsigned short* __restrict__ Bt,  // [N][K] bf16
    const float* __restrict__ bias,         // [N]
    OutT* __restrict__ out,                 // [M][N]  (or vT when VTRANS)
    int M, int N, int K)
{
  __shared__ __align__(16) char lds[32768];
  char* As = lds;
  char* Bs = lds + 16384;
  const int tid  = threadIdx.x;
  const int w    = tid >> 6, lane = tid & 63;
  const int id   = swz_id();
  const int bm   = (id >> 3) * 128, bn = (id & 7) * 128;
  const int wrow = (w >> 1) * 64, wcol = (w & 1) * 64;
  const int l15  = lane & 15, l4 = lane >> 4;

  f32x4 acc[4][4] = {};

  const int srow = lane >> 3;
  const int sc   = lane & 7;

  for (int k0 = 0; k0 < K; k0 += 64) {
    __syncthreads();   // previous iter's frag reads done before overwrite
#pragma unroll
    for (int j = 0; j < 4; ++j) {
      const int ch  = w * 4 + j;
      const int row = ch * 8 + srow;
      const int kc  = sc ^ (row & 7);
      const char* ga = (const char*)(A  + (size_t)(bm + row) * K + k0) + kc * 16;
      const char* gb = (const char*)(Bt + (size_t)(bn + row) * K + k0) + kc * 16;
      gl2lds16(ga, As + ch * 1024 + lane * 16);
      gl2lds16(gb, Bs + ch * 1024 + lane * 16);
    }
    __syncthreads();   // compiler drains vmcnt before s_barrier

#pragma unroll
    for (int ks = 0; ks < 2; ++ks) {
      bf16x8 af[4], bf[4];
#pragma unroll
      for (int i = 0; i < 4; ++i) {
        const int m  = wrow + i * 16 + l15;
        const int n  = wcol + i * 16 + l15;
        const int kc = ks * 4 + l4;
        af[i] = *(const bf16x8*)(As + m * 128 + ((kc ^ (m & 7)) * 16));
        bf[i] = *(const bf16x8*)(Bs + n * 128 + ((kc ^ (n & 7)) * 16));
      }
#pragma unroll
      for (int i = 0; i < 4; ++i)
#pragma unroll
        for (int j = 0; j < 4; ++j)
          acc[i][j] = __builtin_amdgcn_mfma_f32_16x16x32_bf16(af[i], bf[j], acc[i][j], 0, 0, 0);
    }
  }

  // epilogue: C/D layout col = lane&15, row = (lane>>4)*4 + reg
#pragma unroll
  for (int j = 0; j < 4; ++j) {
    const int col = bn + wcol + j * 16 + l15;
    const float bv = bias[col];
    if constexpr (VTRANS) {
      const int e = wcol + j * 16 + l15;   // col within head
      const int h = bn >> 7;               // head index
#pragma unroll
      for (int i = 0; i < 4; ++i) {
        const int m = bm + wrow + i * 16 + l4 * 4;   // 4 consecutive global rows
        const int b = m >> 13, t = m & 8191;
        union { unsigned short u[4]; uint2 v; } pk;
#pragma unroll
        for (int r = 0; r < 4; ++r) pk.u[r] = f2b(acc[i][j][r] + bv);
        *(uint2*)((unsigned short*)out + ((size_t)(b * H_ + h) * D_ + e) * T_ + t) = pk.v;
      }
    } else {
#pragma unroll
      for (int i = 0; i < 4; ++i) {
        const int rbase = bm + wrow + i * 16 + l4 * 4;
#pragma unroll
        for (int r = 0; r < 4; ++r) {
          const float val = acc[i][j][r] + bv;
          if constexpr (sizeof(OutT) == 4)
            out[(size_t)(rbase + r) * N + col] = val;
          else
            ((unsigned short*)out)[(size_t)(rbase + r) * N + col] = f2b(val);
        }
      }
    }
  }
}

// ---------------------------------------------------------------- fused q/k projection
// GEMM (M x 1024 x 1024) + bias + softmax over the 128-col head segment.
// 4 waves in 4x1: each wave owns 32 full rows x 128 cols -> acc[2][8].
// KMODE:  write kT bf16 [32][128][8192] (transposed) + atomic ksum[bh][d]
//         (ksum accumulated from the bf16-ROUNDED values so dinv's denominator
//          matches what ctx consumes).
// !KMODE: round q to bf16, write qb [M][1024], compute dinv[bh][t]=1/(q.ksum).
// grid must be (8, 256).
template<bool KMODE>
__global__ __launch_bounds__(256) void qk_gemm_softmax(
    const unsigned short* __restrict__ A,    // [M][1024] bf16 (x)
    const unsigned short* __restrict__ Bt,   // [1024][1024] bf16 (W^T)
    const float* __restrict__ bias,          // [1024]
    unsigned short* __restrict__ kT,         // KMODE out
    unsigned short* __restrict__ qb,         // !KMODE out
    float* __restrict__ ksum,                // KMODE atomic accum [32][128] (pre-zeroed)
    const float* __restrict__ ksum_in,       // !KMODE in
    float* __restrict__ dinv)                // !KMODE out [32][8192]
{
  __shared__ __align__(16) char lds[32768];
  char* As = lds;
  char* Bs = lds + 16384;
  const int tid  = threadIdx.x;
  const int w    = tid >> 6, lane = tid & 63;
  const int id   = swz_id();
  const int bm   = (id >> 3) * 128, bn = (id & 7) * 128;
  const int wrow = w * 32;
  const int l15  = lane & 15, l4 = lane >> 4;

  f32x4 acc[2][8] = {};
  const int srow = lane >> 3;
  const int sc   = lane & 7;

  for (int k0 = 0; k0 < 1024; k0 += 64) {
    __syncthreads();
#pragma unroll
    for (int j = 0; j < 4; ++j) {
      const int ch  = w * 4 + j;
      const int row = ch * 8 + srow;
      const int kc  = sc ^ (row & 7);
      gl2lds16((const char*)(A  + (size_t)(bm + row) * 1024 + k0) + kc * 16, As + ch * 1024 + lane * 16);
      gl2lds16((const char*)(Bt + (size_t)(bn + row) * 1024 + k0) + kc * 16, Bs + ch * 1024 + lane * 16);
    }
    __syncthreads();

#pragma unroll
    for (int ks = 0; ks < 2; ++ks) {
      bf16x8 af[2], bf[8];
      const int kc = ks * 4 + l4;
#pragma unroll
      for (int i = 0; i < 2; ++i) {
        const int m = wrow + i * 16 + l15;
        af[i] = *(const bf16x8*)(As + m * 128 + ((kc ^ (m & 7)) * 16));
      }
#pragma unroll
      for (int j = 0; j < 8; ++j) {
        const int n = j * 16 + l15;
        bf[j] = *(const bf16x8*)(Bs + n * 128 + ((kc ^ (n & 7)) * 16));
      }
#pragma unroll
      for (int i = 0; i < 2; ++i)
#pragma unroll
        for (int j = 0; j < 8; ++j)
          acc[i][j] = __builtin_amdgcn_mfma_f32_16x16x32_bf16(af[i], bf[j], acc[i][j], 0, 0, 0);
    }
  }

  // ---- bias + softmax over 128 cols of each row (in-register) ----
  float bvj[8];
#pragma unroll
  for (int j = 0; j < 8; ++j) bvj[j] = bias[bn + j * 16 + l15];

#pragma unroll
  for (int i = 0; i < 2; ++i)
#pragma unroll
    for (int r = 0; r < 4; ++r) {
      float v[8];
      float mx = -1e30f;
#pragma unroll
      for (int j = 0; j < 8; ++j) { v[j] = acc[i][j][r] + bvj[j]; mx = fmaxf(mx, v[j]); }
#pragma unroll
      for (int off = 8; off > 0; off >>= 1) mx = fmaxf(mx, __shfl_xor(mx, off, 64));
      float s = 0.f;
#pragma unroll
      for (int j = 0; j < 8; ++j) { v[j] = expf(v[j] - mx); s += v[j]; }
#pragma unroll
      for (int off = 8; off > 0; off >>= 1) s += __shfl_xor(s, off, 64);
      const float inv = 1.0f / s;
#pragma unroll
      for (int j = 0; j < 8; ++j) acc[i][j][r] = v[j] * inv;
    }

  const int h  = bn >> 7;
  const int b  = bm >> 13;          // all 128 rows of this block share b
  const int bh = b * 8 + h;

  if constexpr (KMODE) {
    float csum[8];
#pragma unroll
    for (int j = 0; j < 8; ++j) csum[j] = 0.f;
#pragma unroll
    for (int j = 0; j < 8; ++j) {
      const int d = j * 16 + l15;
#pragma unroll
      for (int i = 0; i < 2; ++i) {
        const int t = (bm + wrow + i * 16 + l4 * 4) & 8191;
        union { unsigned short u[4]; uint2 v2; } pk;
#pragma unroll
        for (int r = 0; r < 4; ++r) {
          const unsigned short us = f2b(acc[i][j][r]);
          pk.u[r] = us;
          csum[j] += b2f(us);
        }
        *(uint2*)(kT + ((size_t)bh * 128 + d) * 8192 + t) = pk.v2;
      }
    }
    // column sums: lanes ^16,^32 share the same col
#pragma unroll
    for (int j = 0; j < 8; ++j) {
      csum[j] += __shfl_xor(csum[j], 16, 64);
      csum[j] += __shfl_xor(csum[j], 32, 64);
    }
    __syncthreads();                 // all frag reads done -> LDS reusable
    float* red = (float*)lds;        // [4][128]
    if (l4 == 0) {
#pragma unroll
      for (int j = 0; j < 8; ++j) red[w * 128 + j * 16 + l15] = csum[j];
    }
    __syncthreads();
    if (tid < 128) {
      const float s2 = red[tid] + red[128 + tid] + red[256 + tid] + red[384 + tid];
      atomicAdd(&ksum[(size_t)bh * 128 + tid], s2);
    }
  } else {
    float ks8[8];
#pragma unroll
    for (int j = 0; j < 8; ++j) ks8[j] = ksum_in[(size_t)bh * 128 + j * 16 + l15];
#pragma unroll
    for (int i = 0; i < 2; ++i)
#pragma unroll
      for (int r = 0; r < 4; ++r) {
        const int m = bm + wrow + i * 16 + l4 * 4 + r;
        float dot = 0.f;
#pragma unroll
        for (int j = 0; j < 8; ++j) {
          acc[i][j][r] = b2f(f2b(acc[i][j][r]));   // use bf16-rounded q everywhere
          dot += acc[i][j][r] * ks8[j];
        }
#pragma unroll
        for (int off = 8; off > 0; off >>= 1) dot += __shfl_xor(dot, off, 64);
        if (l15 == 0) dinv[(size_t)bh * 8192 + (m & 8191)] = 1.0f / dot;
#pragma unroll
        for (int j = 0; j < 8; ++j)
          qb[(size_t)m * 1024 + bn + j * 16 + l15] = f2b(acc[i][j][r]);
      }
  }
}

// ---------------------------------------------------------------- ctx partials via MFMA
// part[kc][bh][e][d] = sum_{t in window kc} kT[bh][d][t] * vT[bh][e][t]
// grid (NKC_=32, 32 bh); window = 256 (4 x BK=64). Plain coalesced f32 stores,
// NO atomics (two-stage reduction replaces the contended atomicAdd epilogue).
__global__ __launch_bounds__(256) void ctx_part_mfma(
    const unsigned short* __restrict__ kT,   // [32][128][8192] bf16
    const unsigned short* __restrict__ vT,   // [32][128][8192] bf16
    float* __restrict__ part)                // [NKC_][32][128][128]  ([e][d] layout)
{
  __shared__ __align__(16) char lds[32768];
  char* As = lds;
  char* Bs = lds + 16384;
  const int tid  = threadIdx.x;
  const int w    = tid >> 6, lane = tid & 63;
  const int bh   = blockIdx.y;
  const int kbase = blockIdx.x * (T_ / NKC_);
  const int wrow = (w >> 1) * 64, wcol = (w & 1) * 64;
  const int l15  = lane & 15, l4 = lane >> 4;
  const unsigned short* A  = kT + (size_t)bh * (D_ * T_);
  const unsigned short* Bt = vT + (size_t)bh * (D_ * T_);

  f32x4 acc[4][4] = {};
  const int srow = lane >> 3;
  const int sc   = lane & 7;

  for (int k0 = kbase; k0 < kbase + (T_ / NKC_); k0 += 64) {
    __syncthreads();
#pragma unroll
    for (int j = 0; j < 4; ++j) {
      const int ch  = w * 4 + j;
      const int row = ch * 8 + srow;
      const int kc  = sc ^ (row & 7);
      gl2lds16((const char*)(A  + (size_t)row * T_ + k0) + kc * 16, As + ch * 1024 + lane * 16);
      gl2lds16((const char*)(Bt + (size_t)row * T_ + k0) + kc * 16, Bs + ch * 1024 + lane * 16);
    }
    __syncthreads();

#pragma unroll
    for (int ks = 0; ks < 2; ++ks) {
      bf16x8 af[4], bf[4];
#pragma unroll
      for (int i = 0; i < 4; ++i) {
        const int m  = wrow + i * 16 + l15;
        const int n  = wcol + i * 16 + l15;
        const int kc = ks * 4 + l4;
        af[i] = *(const bf16x8*)(As + m * 128 + ((kc ^ (m & 7)) * 16));
        bf[i] = *(const bf16x8*)(Bs + n * 128 + ((kc ^ (n & 7)) * 16));
      }
#pragma unroll
      for (int i = 0; i < 4; ++i)
#pragma unroll
        for (int j = 0; j < 4; ++j)
          acc[i][j] = __builtin_amdgcn_mfma_f32_16x16x32_bf16(af[i], bf[j], acc[i][j], 0, 0, 0);
    }
  }

  // partial store: part[kc][bh][e][d], d contiguous -> f32x4 per (i,j)
  float* cb = part + ((size_t)blockIdx.x * 32 + bh) * (D_ * D_);
#pragma unroll
  for (int j = 0; j < 4; ++j) {
    const int e = wcol + j * 16 + l15;
#pragma unroll
    for (int i = 0; i < 4; ++i) {
      const int dbase = wrow + i * 16 + l4 * 4;
      *(f32x4*)&cb[(size_t)e * D_ + dbase] = acc[i][j];
    }
  }
}

// ---------------------------------------------------------------- ctx reduce -> bf16
// ctxTb[bh][e][d] = f2b( sum_kc part[kc][bh][e][d] ).  512 blocks x 256 thr x 4 f32.
__global__ __launch_bounds__(256) void ctx_reduce(
    const float* __restrict__ part, unsigned short* __restrict__ ctxTb)
{
  const size_t i = ((size_t)blockIdx.x * 256 + threadIdx.x) * 4;
  float4 a = {0.f, 0.f, 0.f, 0.f};
#pragma unroll 4
  for (int p = 0; p < NKC_; ++p) {
    float4 v = *(const float4*)(part + (size_t)p * (32 * D_ * D_) + i);
    a.x += v.x; a.y += v.y; a.z += v.z; a.w += v.w;
  }
  union { unsigned short u[4]; uint2 v2; } pk;
  pk.u[0] = f2b(a.x); pk.u[1] = f2b(a.y); pk.u[2] = f2b(a.z); pk.u[3] = f2b(a.w);
  *(uint2*)(ctxTb + i) = pk.v2;
}

// ---------------------------------------------------------------- y via MFMA
// y[t][e] = (sum_d qb[t][d]*ctxTb[e][d]) * dinv[t] + qb[t][e]  -> yb bf16
// Same 128x128 structure, K=128 (2 BK iters). grid must be (8, 256).
__global__ __launch_bounds__(256) void y_mfma(
    const unsigned short* __restrict__ qb,     // [M][1024] bf16 (softmaxed q)
    const unsigned short* __restrict__ ctxTb,  // [32][128][128] bf16  ctxT[e][d]
    const float* __restrict__ dinv,            // [32][8192]
    unsigned short* __restrict__ yb)           // [M][1024] bf16
{
  __shared__ __align__(16) char lds[32768];
  char* As = lds;
  char* Bs = lds + 16384;
  const int tid  = threadIdx.x;
  const int w    = tid >> 6, lane = tid & 63;
  const int id   = swz_id();
  const int bm   = (id >> 3) * 128, bn = (id & 7) * 128;
  const int wrow = (w >> 1) * 64, wcol = (w & 1) * 64;
  const int l15  = lane & 15, l4 = lane >> 4;
  const int h = bn >> 7, b = bm >> 13, bh = b * 8 + h;
  const unsigned short* Bt = ctxTb + (size_t)bh * (D_ * D_);

  f32x4 acc[4][4] = {};
  const int srow = lane >> 3;
  const int sc   = lane & 7;

#pragma unroll
  for (int k0 = 0; k0 < 128; k0 += 64) {
    __syncthreads();
#pragma unroll
    for (int j = 0; j < 4; ++j) {
      const int ch  = w * 4 + j;
      const int row = ch * 8 + srow;
      const int kc  = sc ^ (row & 7);
      gl2lds16((const char*)(qb + (size_t)(bm + row) * 1024 + bn + k0) + kc * 16, As + ch * 1024 + lane * 16);
      gl2lds16((const char*)(Bt + (size_t)row * 128 + k0) + kc * 16, Bs + ch * 1024 + lane * 16);
    }
    __syncthreads();

#pragma unroll
    for (int ks = 0; ks < 2; ++ks) {
      bf16x8 af[4], bf[4];
#pragma unroll
      for (int i = 0; i < 4; ++i) {
        const int m  = wrow + i * 16 + l15;
        const int n  = wcol + i * 16 + l15;
        const int kc = ks * 4 + l4;
        af[i] = *(const bf16x8*)(As + m * 128 + ((kc ^ (m & 7)) * 16));
        bf[i] = *(const bf16x8*)(Bs + n * 128 + ((kc ^ (n & 7)) * 16));
      }
#pragma unroll
      for (int i = 0; i < 4; ++i)
#pragma unroll
        for (int j = 0; j < 4; ++j)
          acc[i][j] = __builtin_amdgcn_mfma_f32_16x16x32_bf16(af[i], bf[j], acc[i][j], 0, 0, 0);
    }
  }

  float di[4][4];
#pragma unroll
  for (int i = 0; i < 4; ++i)
#pragma unroll
    for (int r = 0; r < 4; ++r)
      di[i][r] = dinv[(size_t)bh * 8192 + ((bm + wrow + i * 16 + l4 * 4 + r) & 8191)];

#pragma unroll
  for (int j = 0; j < 4; ++j) {
    const int col = bn + wcol + j * 16 + l15;
#pragma unroll
    for (int i = 0; i < 4; ++i) {
      const int m = bm + wrow + i * 16 + l4 * 4;
#pragma unroll
      for (int r = 0; r < 4; ++r) {
        const float qv = b2f(qb[(size_t)(m + r) * 1024 + col]);
        yb[(size_t)(m + r) * 1024 + col] = f2b(fmaf(acc[i][j][r], di[i][r], qv));
      }
    }
  }
}

// ---------------------------------------------------------------- conversions
// fp32 -> bf16, count must be divisible by 2048 (grid sized exactly)
__global__ __launch_bounds__(256) void conv_bf16(
    const float* __restrict__ in, unsigned short* __restrict__ out)
{
  const size_t i = ((size_t)blockIdx.x * 256 + threadIdx.x) * 8;
  float4 a = *(const float4*)(in + i);
  float4 b = *(const float4*)(in + i + 4);
  union { unsigned short s[8]; uint4 v; } pk;
  pk.s[0] = f2b(a.x); pk.s[1] = f2b(a.y); pk.s[2] = f2b(a.z); pk.s[3] = f2b(a.w);
  pk.s[4] = f2b(b.x); pk.s[5] = f2b(b.y); pk.s[6] = f2b(b.z); pk.s[7] = f2b(b.w);
  *(uint4*)(out + i) = pk.v;
}

// W[K=1024][N=1024] fp32 -> Wt[N][K] bf16 (transpose + cast), 32x32 LDS tiles
__global__ __launch_bounds__(256) void convT_w(
    const float* __restrict__ W, unsigned short* __restrict__ Wt)
{
  __shared__ float s[32][33];
  const int k0 = blockIdx.x * 32, n0 = blockIdx.y * 32;
  const int tx = threadIdx.x & 31, ty = threadIdx.x >> 5;   // 32 x 8
#pragma unroll
  for (int r = ty; r < 32; r += 8) s[r][tx] = W[(size_t)(k0 + r) * 1024 + n0 + tx];
  __syncthreads();
#pragma unroll
  for (int r = ty; r < 32; r += 8) Wt[(size_t)(n0 + r) * 1024 + k0 + tx] = f2b(s[tx][r]);
}

// ---------------------------------------------------------------- launch
extern "C" void kernel_launch(void* const* d_in, const int* in_sizes, int n_in,
                              void* d_out, int out_size, void* d_ws, size_t ws_size,
                              hipStream_t stream)
{
  const float* x  = (const float*)d_in[0];
  const float* Wq = (const float*)d_in[1];
  const float* bq = (const float*)d_in[2];
  const float* Wk = (const float*)d_in[3];
  const float* bk = (const float*)d_in[4];
  const float* Wv = (const float*)d_in[5];
  const float* bv = (const float*)d_in[6];
  const float* Wp = (const float*)d_in[7];
  const float* bp = (const float*)d_in[8];
  float* out = (float*)d_out;

  // workspace layout (MiB offsets):
  //   xb    bf16 [M][C]          @   0  (64)   -- reused as yb by y_mfma
  //   qb    bf16 [M][C]          @  64  (64)
  //   kT    bf16 [32][128][8192] @ 128  (64)
  //   vT    bf16 [32][128][8192] @ 192  (64)
  //   Wt    bf16 4x[N][K]        @ 256  (8)
  //   ksum  fp32 [32][128]       @ 264  (16 KiB)
  //   dinv  fp32 [32][8192]      @ 265  (1)
  //   ctxTb bf16 [32][128][128]  @ 266  (1)
  //   part  fp32 [32][32][128^2] @ 268  (64)    total ~332 MiB
  char* w = (char*)d_ws;
  unsigned short* xb  = (unsigned short*)w;
  unsigned short* qb  = (unsigned short*)(w + (64UL  << 20));
  unsigned short* kT  = (unsigned short*)(w + (128UL << 20));
  unsigned short* vT  = (unsigned short*)(w + (192UL << 20));
  unsigned short* Wtq = (unsigned short*)(w + (256UL << 20));
  unsigned short* Wtk = Wtq + 1024*1024;
  unsigned short* Wtv = Wtk + 1024*1024;
  unsigned short* Wtp = Wtv + 1024*1024;
  float* ksum  = (float*)(w + (264UL << 20));
  float* dinv  = (float*)(w + (265UL << 20));
  unsigned short* ctxTb = (unsigned short*)(w + (266UL << 20));
  float* part  = (float*)(w + (268UL << 20));
  unsigned short* yb = xb;   // xb dead after q projection

  hipMemsetAsync(ksum, 0, 16384, stream);   // only ksum needs zeroing now

  dim3 blk(256);
  dim3 gconvT(32, 32);
  dim3 ggemm(C_/128, M_/128);   // (8, 256)

  conv_bf16<<<dim3(M_*C_/2048), blk, 0, stream>>>(x, xb);
  convT_w<<<gconvT, blk, 0, stream>>>(Wq, Wtq);
  convT_w<<<gconvT, blk, 0, stream>>>(Wk, Wtk);
  convT_w<<<gconvT, blk, 0, stream>>>(Wv, Wtv);
  convT_w<<<gconvT, blk, 0, stream>>>(Wp, Wtp);

  // k projection (fused softmax + transposed bf16 store + ksum)
  qk_gemm_softmax<true><<<ggemm, blk, 0, stream>>>(xb, Wtk, bk, kT, nullptr, ksum, nullptr, nullptr);
  // v projection (transposed bf16 store)
  mfma_gemm_bias<unsigned short, true><<<ggemm, blk, 0, stream>>>(xb, Wtv, bv, vT, M_, C_, C_);
  // q projection (fused softmax + dinv; needs completed ksum)
  qk_gemm_softmax<false><<<ggemm, blk, 0, stream>>>(xb, Wtq, bq, nullptr, qb, nullptr, ksum, dinv);

  ctx_part_mfma<<<dim3(NKC_, B_*H_), blk, 0, stream>>>(kT, vT, part);
  ctx_reduce   <<<dim3(32*D_*D_/1024), blk, 0, stream>>>(part, ctxTb);
  y_mfma<<<ggemm, blk, 0, stream>>>(qb, ctxTb, dinv, yb);

  mfma_gemm_bias<float><<<ggemm, blk, 0, stream>>>(yb, Wtp, bp, out, M_, C_, C_);
}

// Round 5
// 708.487 us; speedup vs baseline: 2.1081x; 1.0831x over previous
//
#include <hip/hip_runtime.h>

// Problem constants
#define B_ 4
#define T_ 8192
#define C_ 1024
#define H_ 8
#define D_ 128
#define M_ (B_*T_)   // 32768 rows
#define NKC_ 32      // ctx k-chunks (t-windows of 256)

typedef __attribute__((ext_vector_type(8))) short bf16x8;   // 8 bf16 = 4 VGPRs
typedef __attribute__((ext_vector_type(4))) float f32x4;

// ---------------------------------------------------------------- bf16 helpers
__device__ __forceinline__ unsigned short f2b(float f) {   // RNE f32->bf16
  union { float f; unsigned int u; } x; x.f = f;
  unsigned int r = x.u + 0x7fffu + ((x.u >> 16) & 1u);
  return (unsigned short)(r >> 16);
}
__device__ __forceinline__ float b2f(unsigned short u) {
  union { float f; unsigned int u; } x; x.u = ((unsigned int)u) << 16; return x.f;
}

// async global->LDS, 16B per lane. LDS dest is wave-uniform base + lane*16.
__device__ __forceinline__ void gl2lds16(const void* g, void* l) {
  __builtin_amdgcn_global_load_lds((const __attribute__((address_space(1))) void*)g,
                                   (__attribute__((address_space(3))) void*)l, 16, 0, 0);
}

// XCD-aware bijective swizzle for (8, 256) grids (nwg=2048, 8 XCDs, chunk=256).
__device__ __forceinline__ int swz_id() {
  const int orig = blockIdx.y * 8 + blockIdx.x;
  return (orig & 7) * 256 + (orig >> 3);
}

// ---------------------------------------------------------------- MFMA GEMM + bias
// out[M,N] = A[M,K](bf16) @ Bt[N,K]^T(bf16) + bias[N]
// 128x128 tile, BK=64, 4 waves in 2x2, each wave 64x64 (4x4 MFMA frags).
// T3 minimum-2-phase pipeline: double-buffered LDS (2 x 32 KB); stage(t+1) is
// issued BEFORE compute(t); ONE __syncthreads per iter (its implicit vmcnt(0)
// drains loads that flew during the whole compute phase -> latency hidden).
// 16B-chunk XOR swizzle in LDS: LDS(row,c) holds logical k-chunk c ^ (row&7).
// VTRANS=true (v projection): out is bf16 vT[32][128][8192]: vT[bh][e][t].
// NOTE: grid must be (8, 256) (swz_id assumption).
template<typename OutT, bool VTRANS=false>
__global__ __launch_bounds__(256) void mfma_gemm_bias(
    const unsigned short* __restrict__ A,   // [M][K] bf16
    const unsigned short* __restrict__ Bt,  // [N][K] bf16
    const float* __restrict__ bias,         // [N]
    OutT* __restrict__ out,                 // [M][N]  (or vT when VTRANS)
    int M, int N, int K)
{
  __shared__ __align__(16) char lds[65536];   // 2 x (As 16K + Bs 16K)
  const int tid  = threadIdx.x;
  const int w    = tid >> 6, lane = tid & 63;
  const int id   = swz_id();
  const int bm   = (id >> 3) * 128, bn = (id & 7) * 128;
  const int wrow = (w >> 1) * 64, wcol = (w & 1) * 64;
  const int l15  = lane & 15, l4 = lane >> 4;
  const int srow = lane >> 3, sc = lane & 7;

  auto stage = [&](int buf, int k0) {
    char* As = lds + buf * 32768;
    char* Bs = As + 16384;
#pragma unroll
    for (int j = 0; j < 4; ++j) {
      const int ch  = w * 4 + j;
      const int row = ch * 8 + srow;
      const int kc  = sc ^ (row & 7);
      gl2lds16((const char*)(A  + (size_t)(bm + row) * K + k0) + kc * 16, As + ch * 1024 + lane * 16);
      gl2lds16((const char*)(Bt + (size_t)(bn + row) * K + k0) + kc * 16, Bs + ch * 1024 + lane * 16);
    }
  };

  f32x4 acc[4][4] = {};
  stage(0, 0);
  __syncthreads();
  int cur = 0;
  for (int k0 = 0; k0 < K; k0 += 64) {
    if (k0 + 64 < K) stage(cur ^ 1, k0 + 64);   // loads fly under compute
    const char* As = lds + cur * 32768;
    const char* Bs = As + 16384;
#pragma unroll
    for (int ks = 0; ks < 2; ++ks) {
      bf16x8 af[4], bf[4];
#pragma unroll
      for (int i = 0; i < 4; ++i) {
        const int m  = wrow + i * 16 + l15;
        const int n  = wcol + i * 16 + l15;
        const int kc = ks * 4 + l4;
        af[i] = *(const bf16x8*)(As + m * 128 + ((kc ^ (m & 7)) * 16));
        bf[i] = *(const bf16x8*)(Bs + n * 128 + ((kc ^ (n & 7)) * 16));
      }
#pragma unroll
      for (int i = 0; i < 4; ++i)
#pragma unroll
        for (int j = 0; j < 4; ++j)
          acc[i][j] = __builtin_amdgcn_mfma_f32_16x16x32_bf16(af[i], bf[j], acc[i][j], 0, 0, 0);
    }
    __syncthreads();   // drains next-stage vmcnt + guards buffer reuse
    cur ^= 1;
  }

  // epilogue: C/D layout col = lane&15, row = (lane>>4)*4 + reg
#pragma unroll
  for (int j = 0; j < 4; ++j) {
    const int col = bn + wcol + j * 16 + l15;
    const float bv = bias[col];
    if constexpr (VTRANS) {
      const int e = wcol + j * 16 + l15;   // col within head
      const int h = bn >> 7;               // head index
#pragma unroll
      for (int i = 0; i < 4; ++i) {
        const int m = bm + wrow + i * 16 + l4 * 4;   // 4 consecutive global rows
        const int b = m >> 13, t = m & 8191;
        union { unsigned short u[4]; uint2 v; } pk;
#pragma unroll
        for (int r = 0; r < 4; ++r) pk.u[r] = f2b(acc[i][j][r] + bv);
        *(uint2*)((unsigned short*)out + ((size_t)(b * H_ + h) * D_ + e) * T_ + t) = pk.v;
      }
    } else {
#pragma unroll
      for (int i = 0; i < 4; ++i) {
        const int rbase = bm + wrow + i * 16 + l4 * 4;
#pragma unroll
        for (int r = 0; r < 4; ++r) {
          const float val = acc[i][j][r] + bv;
          if constexpr (sizeof(OutT) == 4)
            out[(size_t)(rbase + r) * N + col] = val;
          else
            ((unsigned short*)out)[(size_t)(rbase + r) * N + col] = f2b(val);
        }
      }
    }
  }
}

// ---------------------------------------------------------------- fused q/k projection
// GEMM (M x 1024 x 1024) + bias + softmax over the 128-col head segment.
// Same dbuf/stage-early pipeline. 4 waves in 4x1: each wave 32 rows x 128 cols.
// KMODE:  write kT bf16 [32][128][8192] (transposed) + atomic ksum[bh][d]
//         (accumulated from bf16-ROUNDED values so dinv matches ctx inputs).
// !KMODE: round q to bf16, write qb [M][1024], compute dinv[bh][t]=1/(q.ksum).
// grid must be (8, 256).
template<bool KMODE>
__global__ __launch_bounds__(256) void qk_gemm_softmax(
    const unsigned short* __restrict__ A,    // [M][1024] bf16 (x)
    const unsigned short* __restrict__ Bt,   // [1024][1024] bf16 (W^T)
    const float* __restrict__ bias,          // [1024]
    unsigned short* __restrict__ kT,         // KMODE out
    unsigned short* __restrict__ qb,         // !KMODE out
    float* __restrict__ ksum,                // KMODE atomic accum [32][128] (pre-zeroed)
    const float* __restrict__ ksum_in,       // !KMODE in
    float* __restrict__ dinv)                // !KMODE out [32][8192]
{
  __shared__ __align__(16) char lds[65536];
  const int tid  = threadIdx.x;
  const int w    = tid >> 6, lane = tid & 63;
  const int id   = swz_id();
  const int bm   = (id >> 3) * 128, bn = (id & 7) * 128;
  const int wrow = w * 32;
  const int l15  = lane & 15, l4 = lane >> 4;
  const int srow = lane >> 3, sc = lane & 7;

  auto stage = [&](int buf, int k0) {
    char* As = lds + buf * 32768;
    char* Bs = As + 16384;
#pragma unroll
    for (int j = 0; j < 4; ++j) {
      const int ch  = w * 4 + j;
      const int row = ch * 8 + srow;
      const int kc  = sc ^ (row & 7);
      gl2lds16((const char*)(A  + (size_t)(bm + row) * 1024 + k0) + kc * 16, As + ch * 1024 + lane * 16);
      gl2lds16((const char*)(Bt + (size_t)(bn + row) * 1024 + k0) + kc * 16, Bs + ch * 1024 + lane * 16);
    }
  };

  f32x4 acc[2][8] = {};
  stage(0, 0);
  __syncthreads();
  int cur = 0;
  for (int k0 = 0; k0 < 1024; k0 += 64) {
    if (k0 + 64 < 1024) stage(cur ^ 1, k0 + 64);
    const char* As = lds + cur * 32768;
    const char* Bs = As + 16384;
#pragma unroll
    for (int ks = 0; ks < 2; ++ks) {
      bf16x8 af[2], bf[8];
      const int kc = ks * 4 + l4;
#pragma unroll
      for (int i = 0; i < 2; ++i) {
        const int m = wrow + i * 16 + l15;
        af[i] = *(const bf16x8*)(As + m * 128 + ((kc ^ (m & 7)) * 16));
      }
#pragma unroll
      for (int j = 0; j < 8; ++j) {
        const int n = j * 16 + l15;
        bf[j] = *(const bf16x8*)(Bs + n * 128 + ((kc ^ (n & 7)) * 16));
      }
#pragma unroll
      for (int i = 0; i < 2; ++i)
#pragma unroll
        for (int j = 0; j < 8; ++j)
          acc[i][j] = __builtin_amdgcn_mfma_f32_16x16x32_bf16(af[i], bf[j], acc[i][j], 0, 0, 0);
    }
    __syncthreads();
    cur ^= 1;
  }

  // ---- bias + softmax over 128 cols of each row (in-register) ----
  float bvj[8];
#pragma unroll
  for (int j = 0; j < 8; ++j) bvj[j] = bias[bn + j * 16 + l15];

#pragma unroll
  for (int i = 0; i < 2; ++i)
#pragma unroll
    for (int r = 0; r < 4; ++r) {
      float v[8];
      float mx = -1e30f;
#pragma unroll
      for (int j = 0; j < 8; ++j) { v[j] = acc[i][j][r] + bvj[j]; mx = fmaxf(mx, v[j]); }
#pragma unroll
      for (int off = 8; off > 0; off >>= 1) mx = fmaxf(mx, __shfl_xor(mx, off, 64));
      float s = 0.f;
#pragma unroll
      for (int j = 0; j < 8; ++j) { v[j] = expf(v[j] - mx); s += v[j]; }
#pragma unroll
      for (int off = 8; off > 0; off >>= 1) s += __shfl_xor(s, off, 64);
      const float inv = 1.0f / s;
#pragma unroll
      for (int j = 0; j < 8; ++j) acc[i][j][r] = v[j] * inv;
    }

  const int h  = bn >> 7;
  const int b  = bm >> 13;          // all 128 rows of this block share b
  const int bh = b * 8 + h;

  if constexpr (KMODE) {
    float csum[8];
#pragma unroll
    for (int j = 0; j < 8; ++j) csum[j] = 0.f;
#pragma unroll
    for (int j = 0; j < 8; ++j) {
      const int d = j * 16 + l15;
#pragma unroll
      for (int i = 0; i < 2; ++i) {
        const int t = (bm + wrow + i * 16 + l4 * 4) & 8191;
        union { unsigned short u[4]; uint2 v2; } pk;
#pragma unroll
        for (int r = 0; r < 4; ++r) {
          const unsigned short us = f2b(acc[i][j][r]);
          pk.u[r] = us;
          csum[j] += b2f(us);
        }
        *(uint2*)(kT + ((size_t)bh * 128 + d) * 8192 + t) = pk.v2;
      }
    }
    // column sums: lanes ^16,^32 share the same col
#pragma unroll
    for (int j = 0; j < 8; ++j) {
      csum[j] += __shfl_xor(csum[j], 16, 64);
      csum[j] += __shfl_xor(csum[j], 32, 64);
    }
    __syncthreads();                 // LDS reusable for reduction
    float* red = (float*)lds;        // [4][128]
    if (l4 == 0) {
#pragma unroll
      for (int j = 0; j < 8; ++j) red[w * 128 + j * 16 + l15] = csum[j];
    }
    __syncthreads();
    if (tid < 128) {
      const float s2 = red[tid] + red[128 + tid] + red[256 + tid] + red[384 + tid];
      atomicAdd(&ksum[(size_t)bh * 128 + tid], s2);
    }
  } else {
    float ks8[8];
#pragma unroll
    for (int j = 0; j < 8; ++j) ks8[j] = ksum_in[(size_t)bh * 128 + j * 16 + l15];
#pragma unroll
    for (int i = 0; i < 2; ++i)
#pragma unroll
      for (int r = 0; r < 4; ++r) {
        const int m = bm + wrow + i * 16 + l4 * 4 + r;
        float dot = 0.f;
#pragma unroll
        for (int j = 0; j < 8; ++j) {
          acc[i][j][r] = b2f(f2b(acc[i][j][r]));   // use bf16-rounded q everywhere
          dot += acc[i][j][r] * ks8[j];
        }
#pragma unroll
        for (int off = 8; off > 0; off >>= 1) dot += __shfl_xor(dot, off, 64);
        if (l15 == 0) dinv[(size_t)bh * 8192 + (m & 8191)] = 1.0f / dot;
#pragma unroll
        for (int j = 0; j < 8; ++j)
          qb[(size_t)m * 1024 + bn + j * 16 + l15] = f2b(acc[i][j][r]);
      }
  }
}

// ---------------------------------------------------------------- ctx partials via MFMA
// part[kc][bh][e][d] = sum_{t in window kc} kT[bh][d][t] * vT[bh][e][t]
// grid (NKC_=32, 32 bh); window = 256 (4 x BK=64). Dbuf pipeline; plain stores.
__global__ __launch_bounds__(256) void ctx_part_mfma(
    const unsigned short* __restrict__ kT,   // [32][128][8192] bf16
    const unsigned short* __restrict__ vT,   // [32][128][8192] bf16
    float* __restrict__ part)                // [NKC_][32][128][128]  ([e][d] layout)
{
  __shared__ __align__(16) char lds[65536];
  const int tid  = threadIdx.x;
  const int w    = tid >> 6, lane = tid & 63;
  const int bh   = blockIdx.y;
  const int kbase = blockIdx.x * (T_ / NKC_);
  const int wrow = (w >> 1) * 64, wcol = (w & 1) * 64;
  const int l15  = lane & 15, l4 = lane >> 4;
  const int srow = lane >> 3, sc = lane & 7;
  const unsigned short* A  = kT + (size_t)bh * (D_ * T_);
  const unsigned short* Bt = vT + (size_t)bh * (D_ * T_);

  auto stage = [&](int buf, int k0) {
    char* As = lds + buf * 32768;
    char* Bs = As + 16384;
#pragma unroll
    for (int j = 0; j < 4; ++j) {
      const int ch  = w * 4 + j;
      const int row = ch * 8 + srow;
      const int kc  = sc ^ (row & 7);
      gl2lds16((const char*)(A  + (size_t)row * T_ + k0) + kc * 16, As + ch * 1024 + lane * 16);
      gl2lds16((const char*)(Bt + (size_t)row * T_ + k0) + kc * 16, Bs + ch * 1024 + lane * 16);
    }
  };

  f32x4 acc[4][4] = {};
  stage(0, kbase);
  __syncthreads();
  int cur = 0;
  for (int k0 = kbase; k0 < kbase + (T_ / NKC_); k0 += 64) {
    if (k0 + 64 < kbase + (T_ / NKC_)) stage(cur ^ 1, k0 + 64);
    const char* As = lds + cur * 32768;
    const char* Bs = As + 16384;
#pragma unroll
    for (int ks = 0; ks < 2; ++ks) {
      bf16x8 af[4], bf[4];
#pragma unroll
      for (int i = 0; i < 4; ++i) {
        const int m  = wrow + i * 16 + l15;
        const int n  = wcol + i * 16 + l15;
        const int kc = ks * 4 + l4;
        af[i] = *(const bf16x8*)(As + m * 128 + ((kc ^ (m & 7)) * 16));
        bf[i] = *(const bf16x8*)(Bs + n * 128 + ((kc ^ (n & 7)) * 16));
      }
#pragma unroll
      for (int i = 0; i < 4; ++i)
#pragma unroll
        for (int j = 0; j < 4; ++j)
          acc[i][j] = __builtin_amdgcn_mfma_f32_16x16x32_bf16(af[i], bf[j], acc[i][j], 0, 0, 0);
    }
    __syncthreads();
    cur ^= 1;
  }

  // partial store: part[kc][bh][e][d], d contiguous -> f32x4 per (i,j)
  float* cb = part + ((size_t)blockIdx.x * 32 + bh) * (D_ * D_);
#pragma unroll
  for (int j = 0; j < 4; ++j) {
    const int e = wcol + j * 16 + l15;
#pragma unroll
    for (int i = 0; i < 4; ++i) {
      const int dbase = wrow + i * 16 + l4 * 4;
      *(f32x4*)&cb[(size_t)e * D_ + dbase] = acc[i][j];
    }
  }
}

// ---------------------------------------------------------------- ctx reduce -> bf16
// ctxTb[bh][e][d] = f2b( sum_kc part[kc][bh][e][d] ).  512 blocks x 256 thr x 4 f32.
__global__ __launch_bounds__(256) void ctx_reduce(
    const float* __restrict__ part, unsigned short* __restrict__ ctxTb)
{
  const size_t i = ((size_t)blockIdx.x * 256 + threadIdx.x) * 4;
  float4 a = {0.f, 0.f, 0.f, 0.f};
#pragma unroll 4
  for (int p = 0; p < NKC_; ++p) {
    float4 v = *(const float4*)(part + (size_t)p * (32 * D_ * D_) + i);
    a.x += v.x; a.y += v.y; a.z += v.z; a.w += v.w;
  }
  union { unsigned short u[4]; uint2 v2; } pk;
  pk.u[0] = f2b(a.x); pk.u[1] = f2b(a.y); pk.u[2] = f2b(a.z); pk.u[3] = f2b(a.w);
  *(uint2*)(ctxTb + i) = pk.v2;
}

// ---------------------------------------------------------------- y via MFMA
// y[t][e] = (sum_d qb[t][d]*ctxTb[e][d]) * dinv[t] + qb[t][e]  -> yb bf16
// Same dbuf structure, K=128 (2 iters). grid must be (8, 256).
__global__ __launch_bounds__(256) void y_mfma(
    const unsigned short* __restrict__ qb,     // [M][1024] bf16 (softmaxed q)
    const unsigned short* __restrict__ ctxTb,  // [32][128][128] bf16  ctxT[e][d]
    const float* __restrict__ dinv,            // [32][8192]
    unsigned short* __restrict__ yb)           // [M][1024] bf16
{
  __shared__ __align__(16) char lds[65536];
  const int tid  = threadIdx.x;
  const int w    = tid >> 6, lane = tid & 63;
  const int id   = swz_id();
  const int bm   = (id >> 3) * 128, bn = (id & 7) * 128;
  const int wrow = (w >> 1) * 64, wcol = (w & 1) * 64;
  const int l15  = lane & 15, l4 = lane >> 4;
  const int srow = lane >> 3, sc = lane & 7;
  const int h = bn >> 7, b = bm >> 13, bh = b * 8 + h;
  const unsigned short* Bt = ctxTb + (size_t)bh * (D_ * D_);

  auto stage = [&](int buf, int k0) {
    char* As = lds + buf * 32768;
    char* Bs = As + 16384;
#pragma unroll
    for (int j = 0; j < 4; ++j) {
      const int ch  = w * 4 + j;
      const int row = ch * 8 + srow;
      const int kc  = sc ^ (row & 7);
      gl2lds16((const char*)(qb + (size_t)(bm + row) * 1024 + bn + k0) + kc * 16, As + ch * 1024 + lane * 16);
      gl2lds16((const char*)(Bt + (size_t)row * 128 + k0) + kc * 16, Bs + ch * 1024 + lane * 16);
    }
  };

  f32x4 acc[4][4] = {};
  stage(0, 0);
  __syncthreads();
  int cur = 0;
#pragma unroll
  for (int k0 = 0; k0 < 128; k0 += 64) {
    if (k0 + 64 < 128) stage(cur ^ 1, k0 + 64);
    const char* As = lds + cur * 32768;
    const char* Bs = As + 16384;
#pragma unroll
    for (int ks = 0; ks < 2; ++ks) {
      bf16x8 af[4], bf[4];
#pragma unroll
      for (int i = 0; i < 4; ++i) {
        const int m  = wrow + i * 16 + l15;
        const int n  = wcol + i * 16 + l15;
        const int kc = ks * 4 + l4;
        af[i] = *(const bf16x8*)(As + m * 128 + ((kc ^ (m & 7)) * 16));
        bf[i] = *(const bf16x8*)(Bs + n * 128 + ((kc ^ (n & 7)) * 16));
      }
#pragma unroll
      for (int i = 0; i < 4; ++i)
#pragma unroll
        for (int j = 0; j < 4; ++j)
          acc[i][j] = __builtin_amdgcn_mfma_f32_16x16x32_bf16(af[i], bf[j], acc[i][j], 0, 0, 0);
    }
    __syncthreads();
    cur ^= 1;
  }

  float di[4][4];
#pragma unroll
  for (int i = 0; i < 4; ++i)
#pragma unroll
    for (int r = 0; r < 4; ++r)
      di[i][r] = dinv[(size_t)bh * 8192 + ((bm + wrow + i * 16 + l4 * 4 + r) & 8191)];

#pragma unroll
  for (int j = 0; j < 4; ++j) {
    const int col = bn + wcol + j * 16 + l15;
#pragma unroll
    for (int i = 0; i < 4; ++i) {
      const int m = bm + wrow + i * 16 + l4 * 4;
#pragma unroll
      for (int r = 0; r < 4; ++r) {
        const float qv = b2f(qb[(size_t)(m + r) * 1024 + col]);
        yb[(size_t)(m + r) * 1024 + col] = f2b(fmaf(acc[i][j][r], di[i][r], qv));
      }
    }
  }
}

// ---------------------------------------------------------------- conversions
// fp32 -> bf16, count must be divisible by 2048 (grid sized exactly)
__global__ __launch_bounds__(256) void conv_bf16(
    const float* __restrict__ in, unsigned short* __restrict__ out)
{
  const size_t i = ((size_t)blockIdx.x * 256 + threadIdx.x) * 8;
  float4 a = *(const float4*)(in + i);
  float4 b = *(const float4*)(in + i + 4);
  union { unsigned short s[8]; uint4 v; } pk;
  pk.s[0] = f2b(a.x); pk.s[1] = f2b(a.y); pk.s[2] = f2b(a.z); pk.s[3] = f2b(a.w);
  pk.s[4] = f2b(b.x); pk.s[5] = f2b(b.y); pk.s[6] = f2b(b.z); pk.s[7] = f2b(b.w);
  *(uint4*)(out + i) = pk.v;
}

// W[K=1024][N=1024] fp32 -> Wt[N][K] bf16 (transpose + cast), 32x32 LDS tiles.
// All four weight matrices in one launch: grid (32, 32, 4).
__global__ __launch_bounds__(256) void convT_w4(
    const float* __restrict__ W0, const float* __restrict__ W1,
    const float* __restrict__ W2, const float* __restrict__ W3,
    unsigned short* __restrict__ Wt0)   // 4 outputs contiguous, 1 MB apart (ushorts)
{
  const int z = blockIdx.z;
  const float* W = (z == 0) ? W0 : (z == 1) ? W1 : (z == 2) ? W2 : W3;
  unsigned short* Wt = Wt0 + (size_t)z * 1024 * 1024;
  __shared__ float s[32][33];
  const int k0 = blockIdx.x * 32, n0 = blockIdx.y * 32;
  const int tx = threadIdx.x & 31, ty = threadIdx.x >> 5;   // 32 x 8
#pragma unroll
  for (int r = ty; r < 32; r += 8) s[r][tx] = W[(size_t)(k0 + r) * 1024 + n0 + tx];
  __syncthreads();
#pragma unroll
  for (int r = ty; r < 32; r += 8) Wt[(size_t)(n0 + r) * 1024 + k0 + tx] = f2b(s[tx][r]);
}

// ---------------------------------------------------------------- launch
extern "C" void kernel_launch(void* const* d_in, const int* in_sizes, int n_in,
                              void* d_out, int out_size, void* d_ws, size_t ws_size,
                              hipStream_t stream)
{
  const float* x  = (const float*)d_in[0];
  const float* Wq = (const float*)d_in[1];
  const float* bq = (const float*)d_in[2];
  const float* Wk = (const float*)d_in[3];
  const float* bk = (const float*)d_in[4];
  const float* Wv = (const float*)d_in[5];
  const float* bv = (const float*)d_in[6];
  const float* Wp = (const float*)d_in[7];
  const float* bp = (const float*)d_in[8];
  float* out = (float*)d_out;

  // workspace layout (MiB offsets):
  //   xb    bf16 [M][C]          @   0  (64)   -- reused as yb by y_mfma
  //   qb    bf16 [M][C]          @  64  (64)
  //   kT    bf16 [32][128][8192] @ 128  (64)
  //   vT    bf16 [32][128][8192] @ 192  (64)
  //   Wt    bf16 4x[N][K]        @ 256  (8)
  //   ksum  fp32 [32][128]       @ 264  (16 KiB)
  //   dinv  fp32 [32][8192]      @ 265  (1)
  //   ctxTb bf16 [32][128][128]  @ 266  (1)
  //   part  fp32 [32][32][128^2] @ 268  (64)    total ~332 MiB
  char* w = (char*)d_ws;
  unsigned short* xb  = (unsigned short*)w;
  unsigned short* qb  = (unsigned short*)(w + (64UL  << 20));
  unsigned short* kT  = (unsigned short*)(w + (128UL << 20));
  unsigned short* vT  = (unsigned short*)(w + (192UL << 20));
  unsigned short* Wtq = (unsigned short*)(w + (256UL << 20));
  unsigned short* Wtk = Wtq + 1024*1024;
  unsigned short* Wtv = Wtk + 1024*1024;
  unsigned short* Wtp = Wtv + 1024*1024;
  float* ksum  = (float*)(w + (264UL << 20));
  float* dinv  = (float*)(w + (265UL << 20));
  unsigned short* ctxTb = (unsigned short*)(w + (266UL << 20));
  float* part  = (float*)(w + (268UL << 20));
  unsigned short* yb = xb;   // xb dead after q projection

  hipMemsetAsync(ksum, 0, 16384, stream);   // only ksum needs zeroing

  dim3 blk(256);
  dim3 ggemm(C_/128, M_/128);   // (8, 256)

  conv_bf16<<<dim3(M_*C_/2048), blk, 0, stream>>>(x, xb);
  convT_w4<<<dim3(32, 32, 4), blk, 0, stream>>>(Wq, Wk, Wv, Wp, Wtq);

  // k projection (fused softmax + transposed bf16 store + ksum)
  qk_gemm_softmax<true><<<ggemm, blk, 0, stream>>>(xb, Wtk, bk, kT, nullptr, ksum, nullptr, nullptr);
  // v projection (transposed bf16 store)
  mfma_gemm_bias<unsigned short, true><<<ggemm, blk, 0, stream>>>(xb, Wtv, bv, vT, M_, C_, C_);
  // q projection (fused softmax + dinv; needs completed ksum)
  qk_gemm_softmax<false><<<ggemm, blk, 0, stream>>>(xb, Wtq, bq, nullptr, qb, nullptr, ksum, dinv);

  ctx_part_mfma<<<dim3(NKC_, B_*H_), blk, 0, stream>>>(kT, vT, part);
  ctx_reduce   <<<dim3(32*D_*D_/1024), blk, 0, stream>>>(part, ctxTb);
  y_mfma<<<ggemm, blk, 0, stream>>>(qb, ctxTb, dinv, yb);

  mfma_gemm_bias<float><<<ggemm, blk, 0, stream>>>(yb, Wtp, bp, out, M_, C_, C_);
}

// Round 6
// 659.708 us; speedup vs baseline: 2.2640x; 1.0739x over previous
//
#include <hip/hip_runtime.h>

// Problem constants
#define B_ 4
#define T_ 8192
#define C_ 1024
#define H_ 8
#define D_ 128
#define M_ (B_*T_)   // 32768 rows
#define NKC_ 32      // ctx k-chunks (t-windows of 256)

typedef __attribute__((ext_vector_type(8))) short bf16x8;   // 8 bf16 = 4 VGPRs
typedef __attribute__((ext_vector_type(4))) float f32x4;

// ---------------------------------------------------------------- bf16 helpers
__device__ __forceinline__ unsigned short f2b(float f) {   // RNE f32->bf16
  union { float f; unsigned int u; } x; x.f = f;
  unsigned int r = x.u + 0x7fffu + ((x.u >> 16) & 1u);
  return (unsigned short)(r >> 16);
}
__device__ __forceinline__ float b2f(unsigned short u) {
  union { float f; unsigned int u; } x; x.u = ((unsigned int)u) << 16; return x.f;
}

// async global->LDS, 16B per lane. LDS dest is wave-uniform base + lane*16.
__device__ __forceinline__ void gl2lds16(const void* g, void* l) {
  __builtin_amdgcn_global_load_lds((const __attribute__((address_space(1))) void*)g,
                                   (__attribute__((address_space(3))) void*)l, 16, 0, 0);
}

// Pipeline sync primitives (T4): counted vmcnt + raw barrier, fenced against
// compiler reordering (sched_barrier(0) - rule #18 family).
__device__ __forceinline__ void pipe_wait8_barrier() {
  asm volatile("s_waitcnt vmcnt(8)" ::: "memory");
  __builtin_amdgcn_s_barrier();
  __builtin_amdgcn_sched_barrier(0);
}
__device__ __forceinline__ void pipe_wait0_barrier() {
  asm volatile("s_waitcnt vmcnt(0)" ::: "memory");
  __builtin_amdgcn_s_barrier();
  __builtin_amdgcn_sched_barrier(0);
}
__device__ __forceinline__ void pipe_release_barrier() {   // end-of-read fence
  __builtin_amdgcn_sched_barrier(0);
  __builtin_amdgcn_s_barrier();
  __builtin_amdgcn_sched_barrier(0);
}

// XCD-aware bijective swizzle for (8, 256) grids (nwg=2048, 8 XCDs, chunk=256).
__device__ __forceinline__ int swz_id() {
  const int orig = blockIdx.y * 8 + blockIdx.x;
  return (orig & 7) * 256 + (orig >> 3);
}

// ---------------------------------------------------------------- MFMA GEMM + bias
// out[M,N] = A[M,K](bf16) @ Bt[N,K]^T(bf16) + bias[N]
// 128x128 tile, BK=64, 4 waves in 2x2, each wave 64x64 (4x4 MFMA frags).
// T4 pipeline: dbuf LDS; stage(t)/stage(t+1) in flight; per iter:
// vmcnt(8)+barrier (stage t landed, t+1 still flying) -> compute -> barrier
// (reads done) -> restage same buffer for t+2. Loads get a FULL iteration of
// flight time instead of one compute phase.
// 16B-chunk XOR swizzle in LDS: LDS(row,c) holds logical k-chunk c ^ (row&7).
// VTRANS=true (v projection): out is bf16 vT[32][128][8192]: vT[bh][e][t].
// NOTE: grid must be (8, 256) (swz_id assumption); K multiple of 128.
template<typename OutT, bool VTRANS=false>
__global__ __launch_bounds__(256) void mfma_gemm_bias(
    const unsigned short* __restrict__ A,   // [M][K] bf16
    const unsigned short* __restrict__ Bt,  // [N][K] bf16
    const float* __restrict__ bias,         // [N]
    OutT* __restrict__ out,                 // [M][N]  (or vT when VTRANS)
    int M, int N, int K)
{
  __shared__ __align__(16) char lds[65536];   // 2 x (As 16K + Bs 16K)
  const int tid  = threadIdx.x;
  const int w    = tid >> 6, lane = tid & 63;
  const int id   = swz_id();
  const int bm   = (id >> 3) * 128, bn = (id & 7) * 128;
  const int wrow = (w >> 1) * 64, wcol = (w & 1) * 64;
  const int l15  = lane & 15, l4 = lane >> 4;
  const int srow = lane >> 3, sc = lane & 7;

  auto stage = [&](int buf, int k0) {
    char* As = lds + buf * 32768;
    char* Bs = As + 16384;
#pragma unroll
    for (int j = 0; j < 4; ++j) {
      const int ch  = w * 4 + j;
      const int row = ch * 8 + srow;
      const int kc  = sc ^ (row & 7);
      gl2lds16((const char*)(A  + (size_t)(bm + row) * K + k0) + kc * 16, As + ch * 1024 + lane * 16);
      gl2lds16((const char*)(Bt + (size_t)(bn + row) * K + k0) + kc * 16, Bs + ch * 1024 + lane * 16);
    }
  };

  f32x4 acc[4][4] = {};
  auto compute = [&](int buf) {
    const char* As = lds + buf * 32768;
    const char* Bs = As + 16384;
#pragma unroll
    for (int ks = 0; ks < 2; ++ks) {
      bf16x8 af[4], bf[4];
#pragma unroll
      for (int i = 0; i < 4; ++i) {
        const int m  = wrow + i * 16 + l15;
        const int n  = wcol + i * 16 + l15;
        const int kc = ks * 4 + l4;
        af[i] = *(const bf16x8*)(As + m * 128 + ((kc ^ (m & 7)) * 16));
        bf[i] = *(const bf16x8*)(Bs + n * 128 + ((kc ^ (n & 7)) * 16));
      }
      __builtin_amdgcn_s_setprio(1);
#pragma unroll
      for (int i = 0; i < 4; ++i)
#pragma unroll
        for (int j = 0; j < 4; ++j)
          acc[i][j] = __builtin_amdgcn_mfma_f32_16x16x32_bf16(af[i], bf[j], acc[i][j], 0, 0, 0);
      __builtin_amdgcn_s_setprio(0);
    }
  };

  const int nt = K >> 6;
  stage(0, 0);
  stage(1, 64);
  int cur = 0;
  for (int t = 0; t < nt - 1; ++t) {
    pipe_wait8_barrier();          // stage(t) landed; stage(t+1) in flight
    compute(cur);
    pipe_release_barrier();        // all waves done reading buf[cur]
    if (t + 2 < nt) stage(cur, (t + 2) << 6);
    cur ^= 1;
  }
  pipe_wait0_barrier();            // last tile
  compute(cur);

  // epilogue: C/D layout col = lane&15, row = (lane>>4)*4 + reg
#pragma unroll
  for (int j = 0; j < 4; ++j) {
    const int col = bn + wcol + j * 16 + l15;
    const float bv = bias[col];
    if constexpr (VTRANS) {
      const int e = wcol + j * 16 + l15;   // col within head
      const int h = bn >> 7;               // head index
#pragma unroll
      for (int i = 0; i < 4; ++i) {
        const int m = bm + wrow + i * 16 + l4 * 4;   // 4 consecutive global rows
        const int b = m >> 13, t = m & 8191;
        union { unsigned short u[4]; uint2 v; } pk;
#pragma unroll
        for (int r = 0; r < 4; ++r) pk.u[r] = f2b(acc[i][j][r] + bv);
        *(uint2*)((unsigned short*)out + ((size_t)(b * H_ + h) * D_ + e) * T_ + t) = pk.v;
      }
    } else {
#pragma unroll
      for (int i = 0; i < 4; ++i) {
        const int rbase = bm + wrow + i * 16 + l4 * 4;
#pragma unroll
        for (int r = 0; r < 4; ++r) {
          const float val = acc[i][j][r] + bv;
          if constexpr (sizeof(OutT) == 4)
            out[(size_t)(rbase + r) * N + col] = val;
          else
            ((unsigned short*)out)[(size_t)(rbase + r) * N + col] = f2b(val);
        }
      }
    }
  }
}

// ---------------------------------------------------------------- fused q/k projection
// GEMM (M x 1024 x 1024) + bias + softmax over the 128-col head segment.
// Same T4 pipeline. 4 waves in 4x1: each wave 32 rows x 128 cols.
// KMODE:  write kT bf16 [32][128][8192] (transposed) + atomic ksum[bh][d]
//         (accumulated from bf16-ROUNDED values so dinv matches ctx inputs).
// !KMODE: round q to bf16, write qb [M][1024], compute dinv[bh][t]=1/(q.ksum).
// grid must be (8, 256).
template<bool KMODE>
__global__ __launch_bounds__(256) void qk_gemm_softmax(
    const unsigned short* __restrict__ A,    // [M][1024] bf16 (x)
    const unsigned short* __restrict__ Bt,   // [1024][1024] bf16 (W^T)
    const float* __restrict__ bias,          // [1024]
    unsigned short* __restrict__ kT,         // KMODE out
    unsigned short* __restrict__ qb,         // !KMODE out
    float* __restrict__ ksum,                // KMODE atomic accum [32][128] (pre-zeroed)
    const float* __restrict__ ksum_in,       // !KMODE in
    float* __restrict__ dinv)                // !KMODE out [32][8192]
{
  __shared__ __align__(16) char lds[65536];
  const int tid  = threadIdx.x;
  const int w    = tid >> 6, lane = tid & 63;
  const int id   = swz_id();
  const int bm   = (id >> 3) * 128, bn = (id & 7) * 128;
  const int wrow = w * 32;
  const int l15  = lane & 15, l4 = lane >> 4;
  const int srow = lane >> 3, sc = lane & 7;

  auto stage = [&](int buf, int k0) {
    char* As = lds + buf * 32768;
    char* Bs = As + 16384;
#pragma unroll
    for (int j = 0; j < 4; ++j) {
      const int ch  = w * 4 + j;
      const int row = ch * 8 + srow;
      const int kc  = sc ^ (row & 7);
      gl2lds16((const char*)(A  + (size_t)(bm + row) * 1024 + k0) + kc * 16, As + ch * 1024 + lane * 16);
      gl2lds16((const char*)(Bt + (size_t)(bn + row) * 1024 + k0) + kc * 16, Bs + ch * 1024 + lane * 16);
    }
  };

  f32x4 acc[2][8] = {};
  auto compute = [&](int buf) {
    const char* As = lds + buf * 32768;
    const char* Bs = As + 16384;
#pragma unroll
    for (int ks = 0; ks < 2; ++ks) {
      bf16x8 af[2], bf[8];
      const int kc = ks * 4 + l4;
#pragma unroll
      for (int i = 0; i < 2; ++i) {
        const int m = wrow + i * 16 + l15;
        af[i] = *(const bf16x8*)(As + m * 128 + ((kc ^ (m & 7)) * 16));
      }
#pragma unroll
      for (int j = 0; j < 8; ++j) {
        const int n = j * 16 + l15;
        bf[j] = *(const bf16x8*)(Bs + n * 128 + ((kc ^ (n & 7)) * 16));
      }
      __builtin_amdgcn_s_setprio(1);
#pragma unroll
      for (int i = 0; i < 2; ++i)
#pragma unroll
        for (int j = 0; j < 8; ++j)
          acc[i][j] = __builtin_amdgcn_mfma_f32_16x16x32_bf16(af[i], bf[j], acc[i][j], 0, 0, 0);
      __builtin_amdgcn_s_setprio(0);
    }
  };

  stage(0, 0);
  stage(1, 64);
  int cur = 0;
  for (int t = 0; t < 15; ++t) {     // nt = 16
    pipe_wait8_barrier();
    compute(cur);
    pipe_release_barrier();
    if (t + 2 < 16) stage(cur, (t + 2) << 6);
    cur ^= 1;
  }
  pipe_wait0_barrier();
  compute(cur);

  // ---- bias + softmax over 128 cols of each row (in-register) ----
  float bvj[8];
#pragma unroll
  for (int j = 0; j < 8; ++j) bvj[j] = bias[bn + j * 16 + l15];

#pragma unroll
  for (int i = 0; i < 2; ++i)
#pragma unroll
    for (int r = 0; r < 4; ++r) {
      float v[8];
      float mx = -1e30f;
#pragma unroll
      for (int j = 0; j < 8; ++j) { v[j] = acc[i][j][r] + bvj[j]; mx = fmaxf(mx, v[j]); }
#pragma unroll
      for (int off = 8; off > 0; off >>= 1) mx = fmaxf(mx, __shfl_xor(mx, off, 64));
      float s = 0.f;
#pragma unroll
      for (int j = 0; j < 8; ++j) { v[j] = expf(v[j] - mx); s += v[j]; }
#pragma unroll
      for (int off = 8; off > 0; off >>= 1) s += __shfl_xor(s, off, 64);
      const float inv = 1.0f / s;
#pragma unroll
      for (int j = 0; j < 8; ++j) acc[i][j][r] = v[j] * inv;
    }

  const int h  = bn >> 7;
  const int b  = bm >> 13;          // all 128 rows of this block share b
  const int bh = b * 8 + h;

  if constexpr (KMODE) {
    float csum[8];
#pragma unroll
    for (int j = 0; j < 8; ++j) csum[j] = 0.f;
#pragma unroll
    for (int j = 0; j < 8; ++j) {
      const int d = j * 16 + l15;
#pragma unroll
      for (int i = 0; i < 2; ++i) {
        const int t = (bm + wrow + i * 16 + l4 * 4) & 8191;
        union { unsigned short u[4]; uint2 v2; } pk;
#pragma unroll
        for (int r = 0; r < 4; ++r) {
          const unsigned short us = f2b(acc[i][j][r]);
          pk.u[r] = us;
          csum[j] += b2f(us);
        }
        *(uint2*)(kT + ((size_t)bh * 128 + d) * 8192 + t) = pk.v2;
      }
    }
    // column sums: lanes ^16,^32 share the same col
#pragma unroll
    for (int j = 0; j < 8; ++j) {
      csum[j] += __shfl_xor(csum[j], 16, 64);
      csum[j] += __shfl_xor(csum[j], 32, 64);
    }
    __syncthreads();                 // LDS reusable for reduction
    float* red = (float*)lds;        // [4][128]
    if (l4 == 0) {
#pragma unroll
      for (int j = 0; j < 8; ++j) red[w * 128 + j * 16 + l15] = csum[j];
    }
    __syncthreads();
    if (tid < 128) {
      const float s2 = red[tid] + red[128 + tid] + red[256 + tid] + red[384 + tid];
      atomicAdd(&ksum[(size_t)bh * 128 + tid], s2);
    }
  } else {
    float ks8[8];
#pragma unroll
    for (int j = 0; j < 8; ++j) ks8[j] = ksum_in[(size_t)bh * 128 + j * 16 + l15];
#pragma unroll
    for (int i = 0; i < 2; ++i)
#pragma unroll
      for (int r = 0; r < 4; ++r) {
        const int m = bm + wrow + i * 16 + l4 * 4 + r;
        float dot = 0.f;
#pragma unroll
        for (int j = 0; j < 8; ++j) {
          acc[i][j][r] = b2f(f2b(acc[i][j][r]));   // use bf16-rounded q everywhere
          dot += acc[i][j][r] * ks8[j];
        }
#pragma unroll
        for (int off = 8; off > 0; off >>= 1) dot += __shfl_xor(dot, off, 64);
        if (l15 == 0) dinv[(size_t)bh * 8192 + (m & 8191)] = 1.0f / dot;
#pragma unroll
        for (int j = 0; j < 8; ++j)
          qb[(size_t)m * 1024 + bn + j * 16 + l15] = f2b(acc[i][j][r]);
      }
  }
}

// ---------------------------------------------------------------- ctx partials via MFMA
// part[kc][bh][e][d] = sum_{t in window kc} kT[bh][d][t] * vT[bh][e][t]
// grid (NKC_=32, 32 bh); window = 256 (4 x BK=64). T4 pipeline; plain stores.
__global__ __launch_bounds__(256) void ctx_part_mfma(
    const unsigned short* __restrict__ kT,   // [32][128][8192] bf16
    const unsigned short* __restrict__ vT,   // [32][128][8192] bf16
    float* __restrict__ part)                // [NKC_][32][128][128]  ([e][d] layout)
{
  __shared__ __align__(16) char lds[65536];
  const int tid  = threadIdx.x;
  const int w    = tid >> 6, lane = tid & 63;
  const int bh   = blockIdx.y;
  const int kbase = blockIdx.x * (T_ / NKC_);
  const int wrow = (w >> 1) * 64, wcol = (w & 1) * 64;
  const int l15  = lane & 15, l4 = lane >> 4;
  const int srow = lane >> 3, sc = lane & 7;
  const unsigned short* A  = kT + (size_t)bh * (D_ * T_);
  const unsigned short* Bt = vT + (size_t)bh * (D_ * T_);

  auto stage = [&](int buf, int k0) {
    char* As = lds + buf * 32768;
    char* Bs = As + 16384;
#pragma unroll
    for (int j = 0; j < 4; ++j) {
      const int ch  = w * 4 + j;
      const int row = ch * 8 + srow;
      const int kc  = sc ^ (row & 7);
      gl2lds16((const char*)(A  + (size_t)row * T_ + k0) + kc * 16, As + ch * 1024 + lane * 16);
      gl2lds16((const char*)(Bt + (size_t)row * T_ + k0) + kc * 16, Bs + ch * 1024 + lane * 16);
    }
  };

  f32x4 acc[4][4] = {};
  auto compute = [&](int buf) {
    const char* As = lds + buf * 32768;
    const char* Bs = As + 16384;
#pragma unroll
    for (int ks = 0; ks < 2; ++ks) {
      bf16x8 af[4], bf[4];
#pragma unroll
      for (int i = 0; i < 4; ++i) {
        const int m  = wrow + i * 16 + l15;
        const int n  = wcol + i * 16 + l15;
        const int kc = ks * 4 + l4;
        af[i] = *(const bf16x8*)(As + m * 128 + ((kc ^ (m & 7)) * 16));
        bf[i] = *(const bf16x8*)(Bs + n * 128 + ((kc ^ (n & 7)) * 16));
      }
      __builtin_amdgcn_s_setprio(1);
#pragma unroll
      for (int i = 0; i < 4; ++i)
#pragma unroll
        for (int j = 0; j < 4; ++j)
          acc[i][j] = __builtin_amdgcn_mfma_f32_16x16x32_bf16(af[i], bf[j], acc[i][j], 0, 0, 0);
      __builtin_amdgcn_s_setprio(0);
    }
  };

  stage(0, kbase);
  stage(1, kbase + 64);
  int cur = 0;
  for (int t = 0; t < 3; ++t) {     // nt = 4
    pipe_wait8_barrier();
    compute(cur);
    pipe_release_barrier();
    if (t + 2 < 4) stage(cur, kbase + ((t + 2) << 6));
    cur ^= 1;
  }
  pipe_wait0_barrier();
  compute(cur);

  // partial store: part[kc][bh][e][d], d contiguous -> f32x4 per (i,j)
  float* cb = part + ((size_t)blockIdx.x * 32 + bh) * (D_ * D_);
#pragma unroll
  for (int j = 0; j < 4; ++j) {
    const int e = wcol + j * 16 + l15;
#pragma unroll
    for (int i = 0; i < 4; ++i) {
      const int dbase = wrow + i * 16 + l4 * 4;
      *(f32x4*)&cb[(size_t)e * D_ + dbase] = acc[i][j];
    }
  }
}

// ---------------------------------------------------------------- ctx reduce -> bf16
// ctxTb[bh][e][d] = f2b( sum_kc part[kc][bh][e][d] ).  512 blocks x 256 thr x 4 f32.
__global__ __launch_bounds__(256) void ctx_reduce(
    const float* __restrict__ part, unsigned short* __restrict__ ctxTb)
{
  const size_t i = ((size_t)blockIdx.x * 256 + threadIdx.x) * 4;
  float4 a = {0.f, 0.f, 0.f, 0.f};
#pragma unroll 4
  for (int p = 0; p < NKC_; ++p) {
    float4 v = *(const float4*)(part + (size_t)p * (32 * D_ * D_) + i);
    a.x += v.x; a.y += v.y; a.z += v.z; a.w += v.w;
  }
  union { unsigned short u[4]; uint2 v2; } pk;
  pk.u[0] = f2b(a.x); pk.u[1] = f2b(a.y); pk.u[2] = f2b(a.z); pk.u[3] = f2b(a.w);
  *(uint2*)(ctxTb + i) = pk.v2;
}

// ---------------------------------------------------------------- y via MFMA
// y[t][e] = (sum_d qb[t][d]*ctxTb[e][d]) * dinv[t] + qb[t][e]  -> yb bf16
// T4 pipeline, K=128 (nt=2). grid must be (8, 256).
__global__ __launch_bounds__(256) void y_mfma(
    const unsigned short* __restrict__ qb,     // [M][1024] bf16 (softmaxed q)
    const unsigned short* __restrict__ ctxTb,  // [32][128][128] bf16  ctxT[e][d]
    const float* __restrict__ dinv,            // [32][8192]
    unsigned short* __restrict__ yb)           // [M][1024] bf16
{
  __shared__ __align__(16) char lds[65536];
  const int tid  = threadIdx.x;
  const int w    = tid >> 6, lane = tid & 63;
  const int id   = swz_id();
  const int bm   = (id >> 3) * 128, bn = (id & 7) * 128;
  const int wrow = (w >> 1) * 64, wcol = (w & 1) * 64;
  const int l15  = lane & 15, l4 = lane >> 4;
  const int srow = lane >> 3, sc = lane & 7;
  const int h = bn >> 7, b = bm >> 13, bh = b * 8 + h;
  const unsigned short* Bt = ctxTb + (size_t)bh * (D_ * D_);

  auto stage = [&](int buf, int k0) {
    char* As = lds + buf * 32768;
    char* Bs = As + 16384;
#pragma unroll
    for (int j = 0; j < 4; ++j) {
      const int ch  = w * 4 + j;
      const int row = ch * 8 + srow;
      const int kc  = sc ^ (row & 7);
      gl2lds16((const char*)(qb + (size_t)(bm + row) * 1024 + bn + k0) + kc * 16, As + ch * 1024 + lane * 16);
      gl2lds16((const char*)(Bt + (size_t)row * 128 + k0) + kc * 16, Bs + ch * 1024 + lane * 16);
    }
  };

  f32x4 acc[4][4] = {};
  auto compute = [&](int buf) {
    const char* As = lds + buf * 32768;
    const char* Bs = As + 16384;
#pragma unroll
    for (int ks = 0; ks < 2; ++ks) {
      bf16x8 af[4], bf[4];
#pragma unroll
      for (int i = 0; i < 4; ++i) {
        const int m  = wrow + i * 16 + l15;
        const int n  = wcol + i * 16 + l15;
        const int kc = ks * 4 + l4;
        af[i] = *(const bf16x8*)(As + m * 128 + ((kc ^ (m & 7)) * 16));
        bf[i] = *(const bf16x8*)(Bs + n * 128 + ((kc ^ (n & 7)) * 16));
      }
      __builtin_amdgcn_s_setprio(1);
#pragma unroll
      for (int i = 0; i < 4; ++i)
#pragma unroll
        for (int j = 0; j < 4; ++j)
          acc[i][j] = __builtin_amdgcn_mfma_f32_16x16x32_bf16(af[i], bf[j], acc[i][j], 0, 0, 0);
      __builtin_amdgcn_s_setprio(0);
    }
  };

  stage(0, 0);
  stage(1, 64);
  pipe_wait8_barrier();    // t=0 of nt=2
  compute(0);
  pipe_release_barrier();
  pipe_wait0_barrier();
  compute(1);

  float di[4][4];
#pragma unroll
  for (int i = 0; i < 4; ++i)
#pragma unroll
    for (int r = 0; r < 4; ++r)
      di[i][r] = dinv[(size_t)bh * 8192 + ((bm + wrow + i * 16 + l4 * 4 + r) & 8191)];

#pragma unroll
  for (int j = 0; j < 4; ++j) {
    const int col = bn + wcol + j * 16 + l15;
#pragma unroll
    for (int i = 0; i < 4; ++i) {
      const int m = bm + wrow + i * 16 + l4 * 4;
#pragma unroll
      for (int r = 0; r < 4; ++r) {
        const float qv = b2f(qb[(size_t)(m + r) * 1024 + col]);
        yb[(size_t)(m + r) * 1024 + col] = f2b(fmaf(acc[i][j][r], di[i][r], qv));
      }
    }
  }
}

// ---------------------------------------------------------------- conversions
// fp32 -> bf16, count must be divisible by 2048 (grid sized exactly)
__global__ __launch_bounds__(256) void conv_bf16(
    const float* __restrict__ in, unsigned short* __restrict__ out)
{
  const size_t i = ((size_t)blockIdx.x * 256 + threadIdx.x) * 8;
  float4 a = *(const float4*)(in + i);
  float4 b = *(const float4*)(in + i + 4);
  union { unsigned short s[8]; uint4 v; } pk;
  pk.s[0] = f2b(a.x); pk.s[1] = f2b(a.y); pk.s[2] = f2b(a.z); pk.s[3] = f2b(a.w);
  pk.s[4] = f2b(b.x); pk.s[5] = f2b(b.y); pk.s[6] = f2b(b.z); pk.s[7] = f2b(b.w);
  *(uint4*)(out + i) = pk.v;
}

// W[K=1024][N=1024] fp32 -> Wt[N][K] bf16 (transpose + cast), 32x32 LDS tiles.
// All four weight matrices in one launch: grid (32, 32, 4).
__global__ __launch_bounds__(256) void convT_w4(
    const float* __restrict__ W0, const float* __restrict__ W1,
    const float* __restrict__ W2, const float* __restrict__ W3,
    unsigned short* __restrict__ Wt0)   // 4 outputs contiguous, 1 MB apart (ushorts)
{
  const int z = blockIdx.z;
  const float* W = (z == 0) ? W0 : (z == 1) ? W1 : (z == 2) ? W2 : W3;
  unsigned short* Wt = Wt0 + (size_t)z * 1024 * 1024;
  __shared__ float s[32][33];
  const int k0 = blockIdx.x * 32, n0 = blockIdx.y * 32;
  const int tx = threadIdx.x & 31, ty = threadIdx.x >> 5;   // 32 x 8
#pragma unroll
  for (int r = ty; r < 32; r += 8) s[r][tx] = W[(size_t)(k0 + r) * 1024 + n0 + tx];
  __syncthreads();
#pragma unroll
  for (int r = ty; r < 32; r += 8) Wt[(size_t)(n0 + r) * 1024 + k0 + tx] = f2b(s[tx][r]);
}

// ---------------------------------------------------------------- launch
extern "C" void kernel_launch(void* const* d_in, const int* in_sizes, int n_in,
                              void* d_out, int out_size, void* d_ws, size_t ws_size,
                              hipStream_t stream)
{
  const float* x  = (const float*)d_in[0];
  const float* Wq = (const float*)d_in[1];
  const float* bq = (const float*)d_in[2];
  const float* Wk = (const float*)d_in[3];
  const float* bk = (const float*)d_in[4];
  const float* Wv = (const float*)d_in[5];
  const float* bv = (const float*)d_in[6];
  const float* Wp = (const float*)d_in[7];
  const float* bp = (const float*)d_in[8];
  float* out = (float*)d_out;

  // workspace layout (MiB offsets):
  //   xb    bf16 [M][C]          @   0  (64)   -- reused as yb by y_mfma
  //   qb    bf16 [M][C]          @  64  (64)
  //   kT    bf16 [32][128][8192] @ 128  (64)
  //   vT    bf16 [32][128][8192] @ 192  (64)
  //   Wt    bf16 4x[N][K]        @ 256  (8)
  //   ksum  fp32 [32][128]       @ 264  (16 KiB)
  //   dinv  fp32 [32][8192]      @ 265  (1)
  //   ctxTb bf16 [32][128][128]  @ 266  (1)
  //   part  fp32 [32][32][128^2] @ 268  (64)    total ~332 MiB
  char* w = (char*)d_ws;
  unsigned short* xb  = (unsigned short*)w;
  unsigned short* qb  = (unsigned short*)(w + (64UL  << 20));
  unsigned short* kT  = (unsigned short*)(w + (128UL << 20));
  unsigned short* vT  = (unsigned short*)(w + (192UL << 20));
  unsigned short* Wtq = (unsigned short*)(w + (256UL << 20));
  unsigned short* Wtk = Wtq + 1024*1024;
  unsigned short* Wtv = Wtk + 1024*1024;
  unsigned short* Wtp = Wtv + 1024*1024;
  float* ksum  = (float*)(w + (264UL << 20));
  float* dinv  = (float*)(w + (265UL << 20));
  unsigned short* ctxTb = (unsigned short*)(w + (266UL << 20));
  float* part  = (float*)(w + (268UL << 20));
  unsigned short* yb = xb;   // xb dead after q projection

  hipMemsetAsync(ksum, 0, 16384, stream);   // only ksum needs zeroing

  dim3 blk(256);
  dim3 ggemm(C_/128, M_/128);   // (8, 256)

  conv_bf16<<<dim3(M_*C_/2048), blk, 0, stream>>>(x, xb);
  convT_w4<<<dim3(32, 32, 4), blk, 0, stream>>>(Wq, Wk, Wv, Wp, Wtq);

  // k projection (fused softmax + transposed bf16 store + ksum)
  qk_gemm_softmax<true><<<ggemm, blk, 0, stream>>>(xb, Wtk, bk, kT, nullptr, ksum, nullptr, nullptr);
  // v projection (transposed bf16 store)
  mfma_gemm_bias<unsigned short, true><<<ggemm, blk, 0, stream>>>(xb, Wtv, bv, vT, M_, C_, C_);
  // q projection (fused softmax + dinv; needs completed ksum)
  qk_gemm_softmax<false><<<ggemm, blk, 0, stream>>>(xb, Wtq, bq, nullptr, qb, nullptr, ksum, dinv);

  ctx_part_mfma<<<dim3(NKC_, B_*H_), blk, 0, stream>>>(kT, vT, part);
  ctx_reduce   <<<dim3(32*D_*D_/1024), blk, 0, stream>>>(part, ctxTb);
  y_mfma<<<ggemm, blk, 0, stream>>>(qb, ctxTb, dinv, yb);

  mfma_gemm_bias<float><<<ggemm, blk, 0, stream>>>(yb, Wtp, bp, out, M_, C_, C_);
}